// Round 6
// baseline (113.061 us; speedup 1.0000x reference)
//
#include <hip/hip_runtime.h>

// PlasticityController: T=128 sequential scan, E=4096 independent 16x16 W tiles.
// Output = W only; bias/troph updates in the reference are dead code.
// One wave64 per edge; lane l owns W[l>>2][(l&3)*4 .. +3].
//
// R3 changes vs R2:
//  - reductions via DPP (VALU) instead of ds_swizzle (LDS pipe): 12 dpp-adds
//    + 2 readlane(63) replace 10 swizzles + 4 readlanes
//  - post tile transposed to postT[i][b] (stride 20 words, 16B-aligned rows,
//    2-way banks): 8 ds_read_b32 -> 2 ds_read_b128
//  - 2-deep register prefetch (A/B slots, t-loop unrolled x2)

namespace {
constexpr int T = 128, B = 8, NB = 256, P = 16;
constexpr int N = NB * P;   // 4096
constexpr int E = 4096;
constexpr int BN = B * N;
constexpr int PST = 20;     // postT row stride in words (16B-aligned, bank-spread)
constexpr float SYN_LR = 0.01f;
constexpr float DMAX   = 0.1f;
}

// ---------- pre-pass: postX = var*(1-s^2)*sqrt(iv/B), preX = elig*sqrt(iv/B)
__global__ __launch_bounds__(256)
void prepass(const float* __restrict__ states,
             const float* __restrict__ var,
             const float* __restrict__ elig,
             const float* __restrict__ inv,
             float* __restrict__ postX,
             float* __restrict__ preX)
{
  const int idx = blockIdx.x * 256 + threadIdx.x;   // float4 index
  const int tb  = idx >> 10;                        // uniform per block
  const float sc = sqrtf(inv[tb] * (1.0f / B));
  const float4 s = reinterpret_cast<const float4*>(states)[idx];
  const float4 v = reinterpret_cast<const float4*>(var)[idx];
  const float4 e = reinterpret_cast<const float4*>(elig)[idx];
  float4 po, pr;
  po.x = v.x * (1.0f - s.x * s.x) * sc;
  po.y = v.y * (1.0f - s.y * s.y) * sc;
  po.z = v.z * (1.0f - s.z * s.z) * sc;
  po.w = v.w * (1.0f - s.w * s.w) * sc;
  pr.x = e.x * sc; pr.y = e.y * sc; pr.z = e.z * sc; pr.w = e.w * sc;
  reinterpret_cast<float4*>(postX)[idx] = po;
  reinterpret_cast<float4*>(preX)[idx]  = pr;
}

// ---------- DPP wave64 sum (pure VALU; total returned as wave-uniform SGPR)
template<int CTRL>
__device__ __forceinline__ float dpp_add(float v) {
  return v + __int_as_float(__builtin_amdgcn_update_dpp(
      0, __float_as_int(v), CTRL, 0xF, 0xF, true));
}

__device__ __forceinline__ float wave_total(float v) {
  v = dpp_add<0xB1>(v);    // quad_perm [1,0,3,2]  -> pair sums
  v = dpp_add<0x4E>(v);    // quad_perm [2,3,0,1]  -> quad sums
  v = dpp_add<0x141>(v);   // row_half_mirror      -> 8-sums
  v = dpp_add<0x140>(v);   // row_mirror           -> 16-row sums
  v = dpp_add<0x142>(v);   // row_bcast15          -> rows accumulate
  v = dpp_add<0x143>(v);   // row_bcast31          -> lane63 = total
  return __int_as_float(__builtin_amdgcn_readlane(__float_as_int(v), 63));
}

template<bool PRE>
__global__ __launch_bounds__(256)
void plasticity_scan(const float* __restrict__ postX,  // PRE: prepass out; else states
                     const float* __restrict__ preX,   // PRE: prepass out; else elig
                     const float* __restrict__ var,    // !PRE only
                     const float* __restrict__ inv,    // !PRE only
                     const float* __restrict__ Win,
                     const int*   __restrict__ rows,
                     const int*   __restrict__ cols,
                     float*       __restrict__ out)
{
  __shared__ __align__(16) float postT[4][16 * PST];  // [i][b], wave-private
  __shared__ __align__(16) float preL [4][B * P];     // [b][j], wave-private

  const int tid = threadIdx.x;
  const float* ivsP = nullptr;
  if constexpr (!PRE) {
    __shared__ float ivs_[T * B];
    for (int k = tid; k < T * B; k += 256) ivs_[k] = sqrtf(inv[k] * (1.0f / B));
    __syncthreads();
    ivsP = ivs_;
  }

  const int wv   = tid >> 6;
  const int lane = tid & 63;
  const int e    = blockIdx.x * 4 + wv;
  const int irow = lane >> 2;        // 0..15
  const int jcol = (lane & 3) * 4;   // 0,4,8,12
  const int roff = rows[e] * P;      // wave-uniform
  const int coff = cols[e] * P;

  float4 w = *reinterpret_cast<const float4*>(Win + (size_t)e * 256 + lane * 4);
  float w2 = wave_total(w.x * w.x + w.y * w.y + w.z * w.z + w.w * w.w);

  // staging lane maps (both give 8x64B coalesced global segments):
  //  post: sbA = lane&7, siA = 2*(lane>>3) -> postT writes 2-way banks (free)
  //  pre : sbB = lane>>3, siB = 2*(lane&7) -> preL b64 writes 2-way (free)
  const int sbA = lane & 7,  siA = (lane >> 3) * 2;
  const int sbB = lane >> 3, siB = (lane & 7) * 2;

  float* pT  = postT[wv];
  float* qL  = preL[wv];
  float* pwA = pT + siA * PST + sbA;   // pair: [siA][sbA], [siA+1][sbA]
  float* qwB = qL + sbB * 16 + siB;    // float2 [sbB][siB..siB+1]

  const float* pSA = postX + (size_t)sbA * N + roff + siA;
  const float* qSB = preX  + (size_t)sbB * N + coff + siB;
  const float* vSA = PRE ? nullptr : (var + (size_t)sbA * N + roff + siA);

  // 2-deep prefetch: A = even t, B = odd t
  float2 pA = *(const float2*)(pSA);
  float2 qA = *(const float2*)(qSB);
  float2 pB = *(const float2*)(pSA + BN);
  float2 qB = *(const float2*)(qSB + BN);
  float2 vA{0.f, 0.f}, vB{0.f, 0.f};
  if constexpr (!PRE) {
    vA = *(const float2*)(vSA);
    vB = *(const float2*)(vSA + BN);
  }

  auto stage = [&](const float2& pR, const float2& qR, const float2& vR, int t) {
    float2 po, pr;
    if constexpr (PRE) {
      po = pR;
      pr = qR;
    } else {
      const float scA = ivsP[t * B + sbA];
      const float scB = ivsP[t * B + sbB];
      po.x = vR.x * (1.0f - pR.x * pR.x) * scA;
      po.y = vR.y * (1.0f - pR.y * pR.y) * scA;
      pr.x = qR.x * scB;
      pr.y = qR.y * scB;
    }
    pwA[0]   = po.x;                   // ds_write2_b32 candidate (offs 0, PST)
    pwA[PST] = po.y;
    *reinterpret_cast<float2*>(qwB) = pr;
  };

  auto compute = [&]() {
    const float4 poL = *reinterpret_cast<const float4*>(pT + irow * PST);
    const float4 poH = *reinterpret_cast<const float4*>(pT + irow * PST + 4);
    const float4 q0 = *reinterpret_cast<const float4*>(qL + 0 * 16 + jcol);
    const float4 q1 = *reinterpret_cast<const float4*>(qL + 1 * 16 + jcol);
    const float4 q2 = *reinterpret_cast<const float4*>(qL + 2 * 16 + jcol);
    const float4 q3 = *reinterpret_cast<const float4*>(qL + 3 * 16 + jcol);
    const float4 q4 = *reinterpret_cast<const float4*>(qL + 4 * 16 + jcol);
    const float4 q5 = *reinterpret_cast<const float4*>(qL + 5 * 16 + jcol);
    const float4 q6 = *reinterpret_cast<const float4*>(qL + 6 * 16 + jcol);
    const float4 q7 = *reinterpret_cast<const float4*>(qL + 7 * 16 + jcol);

    float h0 = 0.f, h1 = 0.f, h2 = 0.f, h3 = 0.f, p2 = 0.f;
#define ACC(pp, q)                                                             \
    p2 = fmaf((pp), (pp), p2);                                                 \
    h0 = fmaf((pp), (q).x, h0);                                                \
    h1 = fmaf((pp), (q).y, h1);                                                \
    h2 = fmaf((pp), (q).z, h2);                                                \
    h3 = fmaf((pp), (q).w, h3);
    ACC(poL.x, q0) ACC(poL.y, q1) ACC(poL.z, q2) ACC(poL.w, q3)
    ACC(poH.x, q4) ACC(poH.y, q5) ACC(poH.z, q6) ACC(poH.w, q7)
#undef ACC

    const float d0 = fmaf(-p2, w.x, h0);
    const float d1 = fmaf(-p2, w.y, h1);
    const float d2 = fmaf(-p2, w.z, h2);
    const float d3 = fmaf(-p2, w.w, h3);

    float dd = fmaf(d0, d0, fmaf(d1, d1, fmaf(d2, d2, d3 * d3)));
    float wd = fmaf(w.x, d0, fmaf(w.y, d1, fmaf(w.z, d2, w.w * d3)));
    const float ddt = wave_total(dd);
    const float wdt = wave_total(wd);

    // clip: min(1, DMAX/dn); rsqrtf(0)=inf -> fmin gives 1 (EPS no-op there)
    const float cl = fminf(1.0f, DMAX * rsqrtf(ddt)) * SYN_LR;

    const float ws  = fmaxf(fmaf(cl, fmaf(cl, ddt, 2.0f * wdt), w2), 0.0f);
    const float wcl = fminf(1.0f, rsqrtf(ws));   // MAX_NORM = 1

    w.x = wcl * fmaf(cl, d0, w.x);
    w.y = wcl * fmaf(cl, d1, w.y);
    w.z = wcl * fmaf(cl, d2, w.z);
    w.w = wcl * fmaf(cl, d3, w.w);
    w2 = ws * (wcl * wcl);
  };

  for (int t = 0; t < T; t += 2) {
    stage(pA, qA, vA, t);
    if (t + 2 < T) {
      pA = *(const float2*)(pSA + (size_t)(t + 2) * BN);
      qA = *(const float2*)(qSB + (size_t)(t + 2) * BN);
      if constexpr (!PRE) vA = *(const float2*)(vSA + (size_t)(t + 2) * BN);
    }
    compute();

    stage(pB, qB, vB, t + 1);
    if (t + 3 < T) {
      pB = *(const float2*)(pSA + (size_t)(t + 3) * BN);
      qB = *(const float2*)(qSB + (size_t)(t + 3) * BN);
      if constexpr (!PRE) vB = *(const float2*)(vSA + (size_t)(t + 3) * BN);
    }
    compute();
  }

  *reinterpret_cast<float4*>(out + (size_t)e * 256 + lane * 4) = w;
}

extern "C" void kernel_launch(void* const* d_in, const int* in_sizes, int n_in,
                              void* d_out, int out_size, void* d_ws, size_t ws_size,
                              hipStream_t stream) {
  const float* states = (const float*)d_in[0];
  const float* elig   = (const float*)d_in[1];
  // d_in[2] = act           : dead (only feeds bias, never affects W)
  const float* inv    = (const float*)d_in[3];
  const float* var    = (const float*)d_in[4];
  const float* Win    = (const float*)d_in[5];
  // d_in[6] = activity_bias : dead
  // d_in[7] = trophic_map   : dead
  const int* rows     = (const int*)d_in[8];
  const int* cols     = (const int*)d_in[9];
  // d_in[10] = active_blocks: all-ones by construction -> mask == 1.0

  float* out = (float*)d_out;

  const size_t need = (size_t)2 * T * B * N * sizeof(float);   // 33.6 MB
  if (ws_size >= need) {
    float* postX = (float*)d_ws;
    float* preX  = postX + (size_t)T * B * N;
    prepass<<<(T * B * N / 4) / 256, 256, 0, stream>>>(states, var, elig, inv,
                                                       postX, preX);
    plasticity_scan<true><<<E / 4, 256, 0, stream>>>(postX, preX, nullptr,
                                                     nullptr, Win, rows, cols, out);
  } else {
    plasticity_scan<false><<<E / 4, 256, 0, stream>>>(states, elig, var, inv,
                                                      Win, rows, cols, out);
  }
}

// Round 9
// 106.959 us; speedup vs baseline: 1.0571x; 1.0571x over previous
//
#include <hip/hip_runtime.h>

// PlasticityController: T=128 sequential scan, E=4096 independent 16x16 W tiles.
// Output = W only; bias/troph updates in the reference are dead code.
//
// R9 (= R7/R8 intent, host-pass fixed):
//  - R7 failure: no MFMA builtin in HOST pass. R8 failure: host stub was a
//    __host__ function, but clang typechecks __global__ bodies in the host
//    pass too -> "call to __host__ from __global__". Fix: stub is __device__.
//  - __builtin_amdgcn_mfma_f32_16x16x32_bf16 (K=32): duplication k -> b =
//    k mod 8 counts each b 4x; fold 0.25 into postT. Every lane-group covers
//    b=0..7, so A/B fragment loads are wave-wide 16B broadcasts.
//  - prepass writes postT/preT [t][n][8 hi bf16 | 8 lo bf16] (32B rows) and
//    postSq[t][n] = sum_b postX^2 (p2 is edge-independent -> precomputed)
//  - scan: zero LDS / zero DS-pipe ops; 3 MFMA + DPP reduce + carried ||W||^2
//  - hi/lo split drops lo*lo (~2^-16 rel) -- invisible vs 6.3e-3 threshold

namespace {
constexpr int T = 128, B = 8, NB = 256, P = 16;
constexpr int N = NB * P;       // 4096
constexpr int E = 4096;
constexpr int BN = B * N;       // 32768
constexpr float SYN_LR = 0.01f;
constexpr float DMAX   = 0.1f;
}

typedef __attribute__((ext_vector_type(8))) short short8v;
typedef __attribute__((ext_vector_type(4))) float float4v;

#if defined(__HIP_DEVICE_COMPILE__)
#define MFMA_B16(A, Bv, C) \
  __builtin_amdgcn_mfma_f32_16x16x32_bf16((A), (Bv), (C), 0, 0, 0)
#else
// host pass typechecks __global__ bodies: stub must be __device__ (never
// codegen'd on host, so the missing builtin is irrelevant there)
static __device__ inline float4v MFMA_B16(short8v, short8v, float4v C) { return C; }
#endif

__device__ __forceinline__ uint32_t bf16_rne(float x) {
  const uint32_t u = __float_as_uint(x);
  return (u + 0x7fffu + ((u >> 16) & 1u)) >> 16;
}

// ---------- DPP wave64 sum (R6-proven; result wave-uniform via readlane)
template<int CTRL>
__device__ __forceinline__ float dpp_add(float v) {
  return v + __int_as_float(__builtin_amdgcn_update_dpp(
      0, __float_as_int(v), CTRL, 0xF, 0xF, true));
}
__device__ __forceinline__ float wave_total(float v) {
  v = dpp_add<0xB1>(v);    // quad_perm [1,0,3,2]
  v = dpp_add<0x4E>(v);    // quad_perm [2,3,0,1]
  v = dpp_add<0x141>(v);   // row_half_mirror
  v = dpp_add<0x140>(v);   // row_mirror
  v = dpp_add<0x142>(v);   // row_bcast15
  v = dpp_add<0x143>(v);   // row_bcast31
  return __int_as_float(__builtin_amdgcn_readlane(__float_as_int(v), 63));
}

// ---------- prepass: split/pack transposed operands + postSq
// thread handles 4 consecutive n of one t; grid = T*4 blocks x 256 thr
__global__ __launch_bounds__(256)
void prepass2(const float* __restrict__ states,
              const float* __restrict__ var,
              const float* __restrict__ elig,
              const float* __restrict__ inv,
              uint4* __restrict__ postT,   // [t*N+n]*2 + {0: hi8, 1: lo8}
              uint4* __restrict__ preT,
              float* __restrict__ postSq)  // [t*N+n]
{
  const int t  = blockIdx.x >> 2;
  const int n4 = ((blockIdx.x & 3) << 8) | threadIdx.x;   // 0..1023
  const int n0 = n4 * 4;
  const size_t base = (size_t)t * BN + n0;

  uint32_t ph[4][4], pl[4][4], qh[4][4], ql[4][4];
  float sq[4] = {0.f, 0.f, 0.f, 0.f};
#pragma unroll
  for (int b = 0; b < 8; ++b) {
    const float sc = sqrtf(inv[t * B + b] * 0.125f);
    const float4 s4 = *reinterpret_cast<const float4*>(states + base + (size_t)b * N);
    const float4 v4 = *reinterpret_cast<const float4*>(var    + base + (size_t)b * N);
    const float4 e4 = *reinterpret_cast<const float4*>(elig   + base + (size_t)b * N);
    const float ss[4] = {s4.x, s4.y, s4.z, s4.w};
    const float vv[4] = {v4.x, v4.y, v4.z, v4.w};
    const float ee[4] = {e4.x, e4.y, e4.z, e4.w};
#pragma unroll
    for (int r = 0; r < 4; ++r) {
      float po = vv[r] * (1.0f - ss[r] * ss[r]) * sc;
      const float pr = ee[r] * sc;
      sq[r] = fmaf(po, po, sq[r]);     // p2 uses UNSCALED postX
      po *= 0.25f;                     // K=32 duplication counts each b 4x
      const uint32_t hp = bf16_rne(po);
      const uint32_t lp = bf16_rne(po - __uint_as_float(hp << 16));
      const uint32_t hq = bf16_rne(pr);
      const uint32_t lq = bf16_rne(pr - __uint_as_float(hq << 16));
      if ((b & 1) == 0) {
        ph[r][b >> 1] = hp;  pl[r][b >> 1] = lp;
        qh[r][b >> 1] = hq;  ql[r][b >> 1] = lq;
      } else {
        ph[r][b >> 1] |= hp << 16;  pl[r][b >> 1] |= lp << 16;
        qh[r][b >> 1] |= hq << 16;  ql[r][b >> 1] |= lq << 16;
      }
    }
  }
  const size_t row0 = (size_t)t * N + n0;
#pragma unroll
  for (int r = 0; r < 4; ++r) {
    const size_t row = row0 + r;
    postT[row * 2]     = make_uint4(ph[r][0], ph[r][1], ph[r][2], ph[r][3]);
    postT[row * 2 + 1] = make_uint4(pl[r][0], pl[r][1], pl[r][2], pl[r][3]);
    preT [row * 2]     = make_uint4(qh[r][0], qh[r][1], qh[r][2], qh[r][3]);
    preT [row * 2 + 1] = make_uint4(ql[r][0], ql[r][1], ql[r][2], ql[r][3]);
  }
  *reinterpret_cast<float4*>(postSq + row0) = make_float4(sq[0], sq[1], sq[2], sq[3]);
}

// ---------- scan: MFMA path, zero LDS
// mfma_f32_16x16x32_bf16: lane l holds A[m=l&15][k=(l>>4)*8+j] (8 contig k),
// B[k=(l>>4)*8+j][n=l&15], D[row=4*(l>>4)+reg][col=l&15]  (m89/m91-verified
// C/D; A/B k-contiguity implied by the ref-checked m97 GEMM ladder).
// Content A[m][k] = 0.25*postX[k mod 8][roff+m] -> identical 16B row load for
// every lane-group (wave-wide broadcast).
__global__ __launch_bounds__(256)
void scan_mfma(const char* __restrict__ postT,
               const char* __restrict__ preT,
               const char* __restrict__ postSq,
               const float* __restrict__ Win,
               const int* __restrict__ rows,
               const int* __restrict__ cols,
               float* __restrict__ out)
{
  const int tid  = threadIdx.x;
  const int wv   = tid >> 6;
  const int lane = tid & 63;
  const int e    = blockIdx.x * 4 + wv;
  const int g    = lane >> 4;        // 0..3
  const int c    = lane & 15;
  const int roff = rows[e] * P;      // wave-uniform
  const int coff = cols[e] * P;

  // lane owns W[4g+r][c], r=0..3 (matches D layout)
  const size_t wbase = (size_t)e * 256 + (size_t)(4 * g) * 16 + c;
  float w0 = Win[wbase +  0];
  float w1 = Win[wbase + 16];
  float w2e = Win[wbase + 32];
  float w3 = Win[wbase + 48];
  float wn2 = wave_total(fmaf(w0, w0, fmaf(w1, w1, fmaf(w2e, w2e, w3 * w3))));

  const int aOff = (roff + c) << 5;        // byte offset into postT (row*32)
  const int bOff = (coff + c) << 5;        // byte offset into preT
  const int sOff = (roff + 4 * g) << 2;    // byte offset into postSq
  constexpr int ABS = N * 32;    // per-t stride of postT/preT
  constexpr int SQS = N * 4;     // per-t stride of postSq

  short8v Ah0, Al0, Bh0, Bl0, Ah1, Al1, Bh1, Bl1;
  float4v sq0, sq1;

#define LOADSLOT(i, ao, bo, so)                                    \
  Ah##i = *(const short8v*)(postT + (ao));                         \
  Al##i = *(const short8v*)(postT + (ao) + 16);                    \
  Bh##i = *(const short8v*)(preT + (bo));                          \
  Bl##i = *(const short8v*)(preT + (bo) + 16);                     \
  sq##i = *(const float4v*)(postSq + (so));

#define STEP(i)                                                               \
  {                                                                           \
    float4v acc = {0.f, 0.f, 0.f, 0.f};                                       \
    acc = MFMA_B16(Al##i, Bh##i, acc);                                        \
    acc = MFMA_B16(Ah##i, Bl##i, acc);                                        \
    acc = MFMA_B16(Ah##i, Bh##i, acc);                                        \
    const float d0 = fmaf(-sq##i[0], w0, acc[0]);                             \
    const float d1 = fmaf(-sq##i[1], w1, acc[1]);                             \
    const float d2 = fmaf(-sq##i[2], w2e, acc[2]);                            \
    const float d3 = fmaf(-sq##i[3], w3, acc[3]);                             \
    const float dd = fmaf(d0, d0, fmaf(d1, d1, fmaf(d2, d2, d3 * d3)));       \
    const float wd = fmaf(w0, d0, fmaf(w1, d1, fmaf(w2e, d2, w3 * d3)));      \
    const float ddt = wave_total(dd);                                         \
    const float wdt = wave_total(wd);                                         \
    const float cl = fminf(1.0f, DMAX * rsqrtf(ddt)) * SYN_LR;                \
    const float ws = fmaxf(fmaf(cl, fmaf(cl, ddt, 2.0f * wdt), wn2), 0.0f);   \
    const float wcl = fminf(1.0f, rsqrtf(ws));                                \
    w0 = wcl * fmaf(cl, d0, w0);                                              \
    w1 = wcl * fmaf(cl, d1, w1);                                              \
    w2e = wcl * fmaf(cl, d2, w2e);                                            \
    w3 = wcl * fmaf(cl, d3, w3);                                              \
    wn2 = ws * (wcl * wcl);                                                   \
  }

  LOADSLOT(0, aOff, bOff, sOff)
  LOADSLOT(1, aOff + ABS, bOff + ABS, sOff + SQS)

  int aN = aOff + 2 * ABS, bN = bOff + 2 * ABS, sN = sOff + 2 * SQS;
  for (int t = 0; t < T; t += 2) {
    STEP(0)
    if (t + 2 < T) { LOADSLOT(0, aN, bN, sN) }
    STEP(1)
    if (t + 3 < T) { LOADSLOT(1, aN + ABS, bN + ABS, sN + SQS) }
    aN += 2 * ABS; bN += 2 * ABS; sN += 2 * SQS;
  }

  out[wbase +  0] = w0;
  out[wbase + 16] = w1;
  out[wbase + 32] = w2e;
  out[wbase + 48] = w3;
#undef LOADSLOT
#undef STEP
}

// ---------- fallback (R1-proven, no workspace needed)
__global__ __launch_bounds__(256)
void plasticity_scan_fb(const float* __restrict__ states,
                        const float* __restrict__ elig,
                        const float* __restrict__ inv,
                        const float* __restrict__ var,
                        const float* __restrict__ Win,
                        const int*   __restrict__ rows,
                        const int*   __restrict__ cols,
                        float*       __restrict__ out)
{
  __shared__ float ivs[T * B];
  __shared__ float postL[4][B * P];
  __shared__ float preL [4][B * P];

  const int tid = threadIdx.x;
  for (int k = tid; k < T * B; k += 256) ivs[k] = inv[k] * (1.0f / B);
  __syncthreads();

  const int wv   = tid >> 6;
  const int lane = tid & 63;
  const int e    = blockIdx.x * 4 + wv;
  const int irow = lane >> 2;
  const int jcol = (lane & 3) * 4;
  const int roff = rows[e] * P;
  const int coff = cols[e] * P;

  float4 w = *reinterpret_cast<const float4*>(Win + (size_t)e * 256 + lane * 4);

  const int k0 = lane, k1 = lane + 64;
  const int b0 = k0 >> 4, i0 = k0 & 15;
  const int b1 = k1 >> 4, i1 = k1 & 15;
  float* pL = postL[wv];
  float* qL = preL[wv];

  for (int t = 0; t < T; ++t) {
    const size_t base = (size_t)t * BN;
    {
      const size_t ga = base + (size_t)b0 * N + roff + i0;
      const size_t gb = base + (size_t)b1 * N + roff + i1;
      const float s0 = states[ga], v0 = var[ga];
      const float s1 = states[gb], v1 = var[gb];
      const size_t ha = base + (size_t)b0 * N + coff + i0;
      const size_t hb = base + (size_t)b1 * N + coff + i1;
      pL[k0] = v0 * (1.0f - s0 * s0);
      pL[k1] = v1 * (1.0f - s1 * s1);
      qL[k0] = elig[ha];
      qL[k1] = elig[hb];
    }
    float h0 = 0.f, h1 = 0.f, h2 = 0.f, h3 = 0.f, p2 = 0.f;
#pragma unroll
    for (int b = 0; b < B; ++b) {
      const float iv = ivs[t * B + b];
      const float pp = pL[b * 16 + irow];
      const float4 q = *reinterpret_cast<const float4*>(qL + b * 16 + jcol);
      const float pv = pp * iv;
      p2 = fmaf(pv, pp, p2);
      h0 = fmaf(pv, q.x, h0);
      h1 = fmaf(pv, q.y, h1);
      h2 = fmaf(pv, q.z, h2);
      h3 = fmaf(pv, q.w, h3);
    }
    float d0 = h0 - p2 * w.x;
    float d1 = h1 - p2 * w.y;
    float d2 = h2 - p2 * w.z;
    float d3 = h3 - p2 * w.w;
    float s = d0 * d0 + d1 * d1 + d2 * d2 + d3 * d3;
#pragma unroll
    for (int off = 32; off > 0; off >>= 1) s += __shfl_xor(s, off, 64);
    const float dn = sqrtf(s);
    const float cl = fminf(1.0f, DMAX / (dn + 1e-8f)) * SYN_LR;
    w.x = fmaf(cl, d0, w.x);
    w.y = fmaf(cl, d1, w.y);
    w.z = fmaf(cl, d2, w.z);
    w.w = fmaf(cl, d3, w.w);
    float ws = w.x * w.x + w.y * w.y + w.z * w.z + w.w * w.w;
#pragma unroll
    for (int off = 32; off > 0; off >>= 1) ws += __shfl_xor(ws, off, 64);
    const float wn = sqrtf(ws);
    const float wcl = fminf(1.0f, 1.0f / (wn + 1e-8f));
    w.x *= wcl; w.y *= wcl; w.z *= wcl; w.w *= wcl;
  }
  *reinterpret_cast<float4*>(out + (size_t)e * 256 + lane * 4) = w;
}

extern "C" void kernel_launch(void* const* d_in, const int* in_sizes, int n_in,
                              void* d_out, int out_size, void* d_ws, size_t ws_size,
                              hipStream_t stream) {
  const float* states = (const float*)d_in[0];
  const float* elig   = (const float*)d_in[1];
  // d_in[2] = act           : dead (only feeds bias, never affects W)
  const float* inv    = (const float*)d_in[3];
  const float* var    = (const float*)d_in[4];
  const float* Win    = (const float*)d_in[5];
  // d_in[6] = activity_bias : dead
  // d_in[7] = trophic_map   : dead
  const int* rows     = (const int*)d_in[8];
  const int* cols     = (const int*)d_in[9];
  // d_in[10] = active_blocks: all-ones by construction -> mask == 1.0

  float* out = (float*)d_out;

  const size_t szT  = (size_t)T * N * 32;      // 16.78 MB each (postT/preT)
  const size_t szS  = (size_t)T * N * 4;       // 2.1 MB (postSq)
  const size_t need = 2 * szT + szS;           // ~35.7 MB
  if (ws_size >= need) {
    char* postT  = (char*)d_ws;
    char* preT   = postT + szT;
    char* postSq = preT + szT;
    prepass2<<<T * 4, 256, 0, stream>>>(states, var, elig, inv,
                                        (uint4*)postT, (uint4*)preT,
                                        (float*)postSq);
    scan_mfma<<<E / 4, 256, 0, stream>>>(postT, preT, postSq, Win,
                                         rows, cols, out);
  } else {
    plasticity_scan_fb<<<E / 4, 256, 0, stream>>>(states, elig, inv, var,
                                                  Win, rows, cols, out);
  }
}

// Round 10
// 97.791 us; speedup vs baseline: 1.1561x; 1.0937x over previous
//
#include <hip/hip_runtime.h>

// PlasticityController: T=128 sequential scan, E=4096 independent 16x16 W tiles.
// Output = W only; bias/troph updates in the reference are dead code.
//
// R10 (R9 is VALU-issue-bound, ~61 VALU-inst/wave/t; cut instructions):
//  - readfirstlane(rows[e]/cols[e]) -> SGPR bases, SALU per-t advance,
//    global_load saddr+const-voffset form: ~13 VALU/t of addressing -> 0
//  - drop pre's lo half (2 MFMAs: Ah*Bh + Al*Bh). Error ~2^-9 rel on hebb
//    -> absmax ~1e-3, threshold 6.29e-3. preT rows 16B (traffic -8MB)
//  - fold -sq_i*w_i into MFMA C-init: MFMA output IS d (saves a chain level)
//  - unconditional 2-deep prefetch (slack in `need` covers the over-read)

namespace {
constexpr int T = 128, B = 8, NB = 256, P = 16;
constexpr int N = NB * P;       // 4096
constexpr int E = 4096;
constexpr int BN = B * N;       // 32768
constexpr float SYN_LR = 0.01f;
constexpr float DMAX   = 0.1f;
}

typedef __attribute__((ext_vector_type(8))) short short8v;
typedef __attribute__((ext_vector_type(4))) float float4v;

#if defined(__HIP_DEVICE_COMPILE__)
#define MFMA_B16(A, Bv, C) \
  __builtin_amdgcn_mfma_f32_16x16x32_bf16((A), (Bv), (C), 0, 0, 0)
#else
// host pass typechecks __global__ bodies; stub must be __device__
static __device__ inline float4v MFMA_B16(short8v, short8v, float4v C) { return C; }
#endif

__device__ __forceinline__ uint32_t bf16_rne(float x) {
  const uint32_t u = __float_as_uint(x);
  return (u + 0x7fffu + ((u >> 16) & 1u)) >> 16;
}

// ---------- DPP wave64 sum (R6-proven; wave-uniform result via readlane)
template<int CTRL>
__device__ __forceinline__ float dpp_add(float v) {
  return v + __int_as_float(__builtin_amdgcn_update_dpp(
      0, __float_as_int(v), CTRL, 0xF, 0xF, true));
}
__device__ __forceinline__ float wave_total(float v) {
  v = dpp_add<0xB1>(v);    // quad_perm [1,0,3,2]
  v = dpp_add<0x4E>(v);    // quad_perm [2,3,0,1]
  v = dpp_add<0x141>(v);   // row_half_mirror
  v = dpp_add<0x140>(v);   // row_mirror
  v = dpp_add<0x142>(v);   // row_bcast15
  v = dpp_add<0x143>(v);   // row_bcast31
  return __int_as_float(__builtin_amdgcn_readlane(__float_as_int(v), 63));
}

// ---------- prepass: packed transposed operands + postSq
// postT row (32B): 8x bf16 hi | 8x bf16 lo of 0.25*postX[b=0..7][n]
// preT  row (16B): 8x bf16 hi of preX[b=0..7][n]
// postSq[t*N+n] = sum_b postX^2 (p2 is edge-independent)
__global__ __launch_bounds__(256)
void prepass2(const float* __restrict__ states,
              const float* __restrict__ var,
              const float* __restrict__ elig,
              const float* __restrict__ inv,
              uint4* __restrict__ postT,
              uint4* __restrict__ preT,
              float* __restrict__ postSq)
{
  const int t  = blockIdx.x >> 2;
  const int n4 = ((blockIdx.x & 3) << 8) | threadIdx.x;   // 0..1023
  const int n0 = n4 * 4;
  const size_t base = (size_t)t * BN + n0;

  uint32_t ph[4][4], pl[4][4], qh[4][4];
  float sq[4] = {0.f, 0.f, 0.f, 0.f};
#pragma unroll
  for (int b = 0; b < 8; ++b) {
    const float sc = sqrtf(inv[t * B + b] * 0.125f);
    const float4 s4 = *reinterpret_cast<const float4*>(states + base + (size_t)b * N);
    const float4 v4 = *reinterpret_cast<const float4*>(var    + base + (size_t)b * N);
    const float4 e4 = *reinterpret_cast<const float4*>(elig   + base + (size_t)b * N);
    const float ss[4] = {s4.x, s4.y, s4.z, s4.w};
    const float vv[4] = {v4.x, v4.y, v4.z, v4.w};
    const float ee[4] = {e4.x, e4.y, e4.z, e4.w};
#pragma unroll
    for (int r = 0; r < 4; ++r) {
      float po = vv[r] * (1.0f - ss[r] * ss[r]) * sc;
      const float pr = ee[r] * sc;
      sq[r] = fmaf(po, po, sq[r]);     // p2 uses UNSCALED postX
      po *= 0.25f;                     // K=32 duplication counts each b 4x
      const uint32_t hp = bf16_rne(po);
      const uint32_t lp = bf16_rne(po - __uint_as_float(hp << 16));
      const uint32_t hq = bf16_rne(pr);
      if ((b & 1) == 0) {
        ph[r][b >> 1] = hp;  pl[r][b >> 1] = lp;  qh[r][b >> 1] = hq;
      } else {
        ph[r][b >> 1] |= hp << 16;  pl[r][b >> 1] |= lp << 16;
        qh[r][b >> 1] |= hq << 16;
      }
    }
  }
  const size_t row0 = (size_t)t * N + n0;
#pragma unroll
  for (int r = 0; r < 4; ++r) {
    const size_t row = row0 + r;
    postT[row * 2]     = make_uint4(ph[r][0], ph[r][1], ph[r][2], ph[r][3]);
    postT[row * 2 + 1] = make_uint4(pl[r][0], pl[r][1], pl[r][2], pl[r][3]);
    preT [row]         = make_uint4(qh[r][0], qh[r][1], qh[r][2], qh[r][3]);
  }
  *reinterpret_cast<float4*>(postSq + row0) = make_float4(sq[0], sq[1], sq[2], sq[3]);
}

// ---------- scan: MFMA path, zero LDS, SGPR-based addressing
// mfma_f32_16x16x32_bf16: A[m=l&15][k=(l>>4)*8+j], B[k][n=l&15],
// D[row=4*(l>>4)+reg][col=l&15] (C/D m89/m91-verified; layout confirmed by
// R9's absmax matching the fp32 path exactly).
__global__ __launch_bounds__(256)
void scan_mfma(const char* __restrict__ postT,
               const char* __restrict__ preT,
               const char* __restrict__ postSq,
               const float* __restrict__ Win,
               const int* __restrict__ rows,
               const int* __restrict__ cols,
               float* __restrict__ out)
{
  const int tid  = threadIdx.x;
  const int wv   = tid >> 6;
  const int lane = tid & 63;
  const int e    = blockIdx.x * 4 + wv;
  const int g    = lane >> 4;        // 0..3
  const int c    = lane & 15;
  // wave-uniform, but divergence analysis can't see it: force SGPR
  const int roff = __builtin_amdgcn_readfirstlane(rows[e]) * P;
  const int coff = __builtin_amdgcn_readfirstlane(cols[e]) * P;

  // lane owns W[4g+r][c], r=0..3 (matches D layout)
  const size_t wbase = (size_t)e * 256 + (size_t)(4 * g) * 16 + c;
  float w0  = Win[wbase +  0];
  float w1  = Win[wbase + 16];
  float w2e = Win[wbase + 32];
  float w3  = Win[wbase + 48];
  float wn2 = wave_total(fmaf(w0, w0, fmaf(w1, w1, fmaf(w2e, w2e, w3 * w3))));

  // uniform (SGPR) bases + constant lane offsets (VGPR)
  const char* pA = postT  + (size_t)roff * 32;
  const char* pB = preT   + (size_t)coff * 16;
  const char* pS = postSq + (size_t)roff * 4;
  const int vA = c << 5;
  const int vB = c << 4;
  const int vS = g << 4;
  constexpr int SA = N * 32, SB = N * 16, SS = N * 4;  // per-t strides

  // 2-deep prefetch slots
  short8v Ah0 = *(const short8v*)(pA + vA);
  short8v Al0 = *(const short8v*)(pA + vA + 16);
  short8v Bh0 = *(const short8v*)(pB + vB);
  float4v sq0 = *(const float4v*)(pS + vS);
  short8v Ah1 = *(const short8v*)(pA + SA + vA);
  short8v Al1 = *(const short8v*)(pA + SA + vA + 16);
  short8v Bh1 = *(const short8v*)(pB + SB + vB);
  float4v sq1 = *(const float4v*)(pS + SS + vS);
  pA += 2 * SA; pB += 2 * SB; pS += 2 * SS;

  // Prefetch is unconditional: final iterations over-read <=2 strides past
  // each array; layout order postT|preT|postSq + 64KB slack keeps it in d_ws.
#define STEP(AH, AL, BH, SQ, AOFF, BOFF, SOFF)                                \
  {                                                                           \
    float4v acc;                                                              \
    acc[0] = -SQ[0] * w0;                                                     \
    acc[1] = -SQ[1] * w1;                                                     \
    acc[2] = -SQ[2] * w2e;                                                    \
    acc[3] = -SQ[3] * w3;                                                     \
    acc = MFMA_B16(AL, BH, acc);                                              \
    acc = MFMA_B16(AH, BH, acc);   /* acc == d = hebb - p2*W */               \
    AH = *(const short8v*)(pA + (AOFF) + vA);                                 \
    AL = *(const short8v*)(pA + (AOFF) + vA + 16);                            \
    BH = *(const short8v*)(pB + (BOFF) + vB);                                 \
    SQ = *(const float4v*)(pS + (SOFF) + vS);                                 \
    const float ddp = fmaf(acc[0], acc[0], fmaf(acc[1], acc[1],               \
                      fmaf(acc[2], acc[2], acc[3] * acc[3])));                \
    const float wdp = fmaf(w0, acc[0], fmaf(w1, acc[1],                       \
                      fmaf(w2e, acc[2], w3 * acc[3])));                       \
    const float ddt = wave_total(ddp);                                        \
    const float wdt = wave_total(wdp);                                        \
    const float cl = fminf(1.0f, DMAX * rsqrtf(ddt)) * SYN_LR;                \
    const float ws = fmaxf(fmaf(cl, fmaf(cl, ddt, 2.0f * wdt), wn2), 0.0f);   \
    const float wcl = fminf(1.0f, rsqrtf(ws));                                \
    w0  = wcl * fmaf(cl, acc[0], w0);                                         \
    w1  = wcl * fmaf(cl, acc[1], w1);                                         \
    w2e = wcl * fmaf(cl, acc[2], w2e);                                        \
    w3  = wcl * fmaf(cl, acc[3], w3);                                         \
    wn2 = ws * (wcl * wcl);                                                   \
  }

  for (int t = 0; t < T; t += 2) {
    STEP(Ah0, Al0, Bh0, sq0, 0, 0, 0)
    STEP(Ah1, Al1, Bh1, sq1, SA, SB, SS)
    pA += 2 * SA; pB += 2 * SB; pS += 2 * SS;
  }
#undef STEP

  out[wbase +  0] = w0;
  out[wbase + 16] = w1;
  out[wbase + 32] = w2e;
  out[wbase + 48] = w3;
}

// ---------- fallback (R1-proven, no workspace needed)
__global__ __launch_bounds__(256)
void plasticity_scan_fb(const float* __restrict__ states,
                        const float* __restrict__ elig,
                        const float* __restrict__ inv,
                        const float* __restrict__ var,
                        const float* __restrict__ Win,
                        const int*   __restrict__ rows,
                        const int*   __restrict__ cols,
                        float*       __restrict__ out)
{
  __shared__ float ivs[T * B];
  __shared__ float postL[4][B * P];
  __shared__ float preL [4][B * P];

  const int tid = threadIdx.x;
  for (int k = tid; k < T * B; k += 256) ivs[k] = inv[k] * (1.0f / B);
  __syncthreads();

  const int wv   = tid >> 6;
  const int lane = tid & 63;
  const int e    = blockIdx.x * 4 + wv;
  const int irow = lane >> 2;
  const int jcol = (lane & 3) * 4;
  const int roff = rows[e] * P;
  const int coff = cols[e] * P;

  float4 w = *reinterpret_cast<const float4*>(Win + (size_t)e * 256 + lane * 4);

  const int k0 = lane, k1 = lane + 64;
  const int b0 = k0 >> 4, i0 = k0 & 15;
  const int b1 = k1 >> 4, i1 = k1 & 15;
  float* pL = postL[wv];
  float* qL = preL[wv];

  for (int t = 0; t < T; ++t) {
    const size_t base = (size_t)t * BN;
    {
      const size_t ga = base + (size_t)b0 * N + roff + i0;
      const size_t gb = base + (size_t)b1 * N + roff + i1;
      const float s0 = states[ga], v0 = var[ga];
      const float s1 = states[gb], v1 = var[gb];
      const size_t ha = base + (size_t)b0 * N + coff + i0;
      const size_t hb = base + (size_t)b1 * N + coff + i1;
      pL[k0] = v0 * (1.0f - s0 * s0);
      pL[k1] = v1 * (1.0f - s1 * s1);
      qL[k0] = elig[ha];
      qL[k1] = elig[hb];
    }
    float h0 = 0.f, h1 = 0.f, h2 = 0.f, h3 = 0.f, p2 = 0.f;
#pragma unroll
    for (int b = 0; b < B; ++b) {
      const float iv = ivs[t * B + b];
      const float pp = pL[b * 16 + irow];
      const float4 q = *reinterpret_cast<const float4*>(qL + b * 16 + jcol);
      const float pv = pp * iv;
      p2 = fmaf(pv, pp, p2);
      h0 = fmaf(pv, q.x, h0);
      h1 = fmaf(pv, q.y, h1);
      h2 = fmaf(pv, q.z, h2);
      h3 = fmaf(pv, q.w, h3);
    }
    float d0 = h0 - p2 * w.x;
    float d1 = h1 - p2 * w.y;
    float d2 = h2 - p2 * w.z;
    float d3 = h3 - p2 * w.w;
    float s = d0 * d0 + d1 * d1 + d2 * d2 + d3 * d3;
#pragma unroll
    for (int off = 32; off > 0; off >>= 1) s += __shfl_xor(s, off, 64);
    const float dn = sqrtf(s);
    const float cl = fminf(1.0f, DMAX / (dn + 1e-8f)) * SYN_LR;
    w.x = fmaf(cl, d0, w.x);
    w.y = fmaf(cl, d1, w.y);
    w.z = fmaf(cl, d2, w.z);
    w.w = fmaf(cl, d3, w.w);
    float ws = w.x * w.x + w.y * w.y + w.z * w.z + w.w * w.w;
#pragma unroll
    for (int off = 32; off > 0; off >>= 1) ws += __shfl_xor(ws, off, 64);
    const float wn = sqrtf(ws);
    const float wcl = fminf(1.0f, 1.0f / (wn + 1e-8f));
    w.x *= wcl; w.y *= wcl; w.z *= wcl; w.w *= wcl;
  }
  *reinterpret_cast<float4*>(out + (size_t)e * 256 + lane * 4) = w;
}

extern "C" void kernel_launch(void* const* d_in, const int* in_sizes, int n_in,
                              void* d_out, int out_size, void* d_ws, size_t ws_size,
                              hipStream_t stream) {
  const float* states = (const float*)d_in[0];
  const float* elig   = (const float*)d_in[1];
  // d_in[2] = act           : dead (only feeds bias, never affects W)
  const float* inv    = (const float*)d_in[3];
  const float* var    = (const float*)d_in[4];
  const float* Win    = (const float*)d_in[5];
  // d_in[6] = activity_bias : dead
  // d_in[7] = trophic_map   : dead
  const int* rows     = (const int*)d_in[8];
  const int* cols     = (const int*)d_in[9];
  // d_in[10] = active_blocks: all-ones by construction -> mask == 1.0

  float* out = (float*)d_out;

  const size_t szA  = (size_t)T * N * 32;      // 16.78 MB postT
  const size_t szB  = (size_t)T * N * 16;      //  8.39 MB preT
  const size_t szS  = (size_t)T * N * 4;       //  2.10 MB postSq
  const size_t need = szA + szB + szS + 65536; // + prefetch over-read slack
  if (ws_size >= need) {
    char* postT  = (char*)d_ws;
    char* preT   = postT + szA;
    char* postSq = preT + szB;
    prepass2<<<T * 4, 256, 0, stream>>>(states, var, elig, inv,
                                        (uint4*)postT, (uint4*)preT,
                                        (float*)postSq);
    scan_mfma<<<E / 4, 256, 0, stream>>>(postT, preT, postSq, Win,
                                         rows, cols, out);
  } else {
    plasticity_scan_fb<<<E / 4, 256, 0, stream>>>(states, elig, inv, var,
                                                  Win, rows, cols, out);
  }
}

// Round 11
// 97.058 us; speedup vs baseline: 1.1649x; 1.0076x over previous
//
#include <hip/hip_runtime.h>

// PlasticityController: T=128 sequential scan, E=4096 independent 16x16 W tiles.
// Output = W only; bias/troph updates in the reference are dead code.
//
// R11 (R10 still VALU-issue-bound at ~44 inst/wave/t; occupancy is capped at
// 4 waves/SIMD by edge-parallelism, so cut instructions):
//  - packed fp32 (v_pk_fma_f32 / v_pk_mul_f32 via float2 ext-vectors +
//    __builtin_elementwise_fma): acc-init 4->2, ddp/wdp 8->6, W-update 8->4.
//    Numerically identical (pk fma = 2 IEEE fmas).
//  - everything else unchanged from R10 (SGPR addressing, 2 MFMA hi/lo,
//    C-init fold, DPP reductions, carried ||W||^2, 2-deep prefetch).

namespace {
constexpr int T = 128, B = 8, NB = 256, P = 16;
constexpr int N = NB * P;       // 4096
constexpr int E = 4096;
constexpr int BN = B * N;       // 32768
constexpr float SYN_LR = 0.01f;
constexpr float DMAX   = 0.1f;
}

typedef __attribute__((ext_vector_type(8))) short short8v;
typedef __attribute__((ext_vector_type(4))) float float4v;
typedef __attribute__((ext_vector_type(2))) float float2v;

#if defined(__HIP_DEVICE_COMPILE__)
#define MFMA_B16(A, Bv, C) \
  __builtin_amdgcn_mfma_f32_16x16x32_bf16((A), (Bv), (C), 0, 0, 0)
#else
// host pass typechecks __global__ bodies; stub must be __device__
static __device__ inline float4v MFMA_B16(short8v, short8v, float4v C) { return C; }
#endif

__device__ __forceinline__ uint32_t bf16_rne(float x) {
  const uint32_t u = __float_as_uint(x);
  return (u + 0x7fffu + ((u >> 16) & 1u)) >> 16;
}

// ---------- DPP wave64 sum (R6-proven; wave-uniform result via readlane)
template<int CTRL>
__device__ __forceinline__ float dpp_add(float v) {
  return v + __int_as_float(__builtin_amdgcn_update_dpp(
      0, __float_as_int(v), CTRL, 0xF, 0xF, true));
}
__device__ __forceinline__ float wave_total(float v) {
  v = dpp_add<0xB1>(v);    // quad_perm [1,0,3,2]
  v = dpp_add<0x4E>(v);    // quad_perm [2,3,0,1]
  v = dpp_add<0x141>(v);   // row_half_mirror
  v = dpp_add<0x140>(v);   // row_mirror
  v = dpp_add<0x142>(v);   // row_bcast15
  v = dpp_add<0x143>(v);   // row_bcast31
  return __int_as_float(__builtin_amdgcn_readlane(__float_as_int(v), 63));
}

// ---------- prepass: packed transposed operands + postSq
// postT row (32B): 8x bf16 hi | 8x bf16 lo of 0.25*postX[b=0..7][n]
// preT  row (16B): 8x bf16 hi of preX[b=0..7][n]
// postSq[t*N+n] = sum_b postX^2 (p2 is edge-independent)
__global__ __launch_bounds__(256)
void prepass2(const float* __restrict__ states,
              const float* __restrict__ var,
              const float* __restrict__ elig,
              const float* __restrict__ inv,
              uint4* __restrict__ postT,
              uint4* __restrict__ preT,
              float* __restrict__ postSq)
{
  const int t  = blockIdx.x >> 2;
  const int n4 = ((blockIdx.x & 3) << 8) | threadIdx.x;   // 0..1023
  const int n0 = n4 * 4;
  const size_t base = (size_t)t * BN + n0;

  uint32_t ph[4][4], pl[4][4], qh[4][4];
  float sq[4] = {0.f, 0.f, 0.f, 0.f};
#pragma unroll
  for (int b = 0; b < 8; ++b) {
    const float sc = sqrtf(inv[t * B + b] * 0.125f);
    const float4 s4 = *reinterpret_cast<const float4*>(states + base + (size_t)b * N);
    const float4 v4 = *reinterpret_cast<const float4*>(var    + base + (size_t)b * N);
    const float4 e4 = *reinterpret_cast<const float4*>(elig   + base + (size_t)b * N);
    const float ss[4] = {s4.x, s4.y, s4.z, s4.w};
    const float vv[4] = {v4.x, v4.y, v4.z, v4.w};
    const float ee[4] = {e4.x, e4.y, e4.z, e4.w};
#pragma unroll
    for (int r = 0; r < 4; ++r) {
      float po = vv[r] * (1.0f - ss[r] * ss[r]) * sc;
      const float pr = ee[r] * sc;
      sq[r] = fmaf(po, po, sq[r]);     // p2 uses UNSCALED postX
      po *= 0.25f;                     // K=32 duplication counts each b 4x
      const uint32_t hp = bf16_rne(po);
      const uint32_t lp = bf16_rne(po - __uint_as_float(hp << 16));
      const uint32_t hq = bf16_rne(pr);
      if ((b & 1) == 0) {
        ph[r][b >> 1] = hp;  pl[r][b >> 1] = lp;  qh[r][b >> 1] = hq;
      } else {
        ph[r][b >> 1] |= hp << 16;  pl[r][b >> 1] |= lp << 16;
        qh[r][b >> 1] |= hq << 16;
      }
    }
  }
  const size_t row0 = (size_t)t * N + n0;
#pragma unroll
  for (int r = 0; r < 4; ++r) {
    const size_t row = row0 + r;
    postT[row * 2]     = make_uint4(ph[r][0], ph[r][1], ph[r][2], ph[r][3]);
    postT[row * 2 + 1] = make_uint4(pl[r][0], pl[r][1], pl[r][2], pl[r][3]);
    preT [row]         = make_uint4(qh[r][0], qh[r][1], qh[r][2], qh[r][3]);
  }
  *reinterpret_cast<float4*>(postSq + row0) = make_float4(sq[0], sq[1], sq[2], sq[3]);
}

// ---------- scan: MFMA path, zero LDS, SGPR addressing, packed fp32 epilogue
// mfma_f32_16x16x32_bf16: A[m=l&15][k=(l>>4)*8+j], B[k][n=l&15],
// D[row=4*(l>>4)+reg][col=l&15] (layout confirmed: R9 absmax == fp32 path).
__global__ __launch_bounds__(256)
void scan_mfma(const char* __restrict__ postT,
               const char* __restrict__ preT,
               const char* __restrict__ postSq,
               const float* __restrict__ Win,
               const int* __restrict__ rows,
               const int* __restrict__ cols,
               float* __restrict__ out)
{
  const int tid  = threadIdx.x;
  const int wv   = tid >> 6;
  const int lane = tid & 63;
  const int e    = blockIdx.x * 4 + wv;
  const int g    = lane >> 4;        // 0..3
  const int c    = lane & 15;
  // wave-uniform, but divergence analysis can't see it: force SGPR
  const int roff = __builtin_amdgcn_readfirstlane(rows[e]) * P;
  const int coff = __builtin_amdgcn_readfirstlane(cols[e]) * P;

  // lane owns W[4g+r][c], r=0..3 (matches D layout)
  const size_t wbase = (size_t)e * 256 + (size_t)(4 * g) * 16 + c;
  float2v w01 = { Win[wbase +  0], Win[wbase + 16] };
  float2v w23 = { Win[wbase + 32], Win[wbase + 48] };
  const float2v t2i = __builtin_elementwise_fma(w01, w01, w23 * w23);
  float wn2 = wave_total(t2i[0] + t2i[1]);

  // uniform (SGPR) bases + constant lane offsets (VGPR)
  const char* pA = postT  + (size_t)roff * 32;
  const char* pB = preT   + (size_t)coff * 16;
  const char* pS = postSq + (size_t)roff * 4;
  const int vA = c << 5;
  const int vB = c << 4;
  const int vS = g << 4;
  constexpr int SA = N * 32, SB = N * 16, SS = N * 4;  // per-t strides

  // 2-deep prefetch slots
  short8v Ah0 = *(const short8v*)(pA + vA);
  short8v Al0 = *(const short8v*)(pA + vA + 16);
  short8v Bh0 = *(const short8v*)(pB + vB);
  float4v sq0 = *(const float4v*)(pS + vS);
  short8v Ah1 = *(const short8v*)(pA + SA + vA);
  short8v Al1 = *(const short8v*)(pA + SA + vA + 16);
  short8v Bh1 = *(const short8v*)(pB + SB + vB);
  float4v sq1 = *(const float4v*)(pS + SS + vS);
  pA += 2 * SA; pB += 2 * SB; pS += 2 * SS;

  // Prefetch is unconditional: final iterations over-read <=2 strides past
  // each array; layout order postT|preT|postSq + 64KB slack keeps it in d_ws.
#define STEP(AH, AL, BH, SQ, AOFF, BOFF, SOFF)                                \
  {                                                                           \
    const float2v sq01 = __builtin_shufflevector(SQ, SQ, 0, 1);               \
    const float2v sq23 = __builtin_shufflevector(SQ, SQ, 2, 3);               \
    const float2v a01 = (-sq01) * w01;        /* v_pk_mul_f32 */              \
    const float2v a23 = (-sq23) * w23;                                        \
    float4v acc = __builtin_shufflevector(a01, a23, 0, 1, 2, 3);              \
    acc = MFMA_B16(AL, BH, acc);                                              \
    acc = MFMA_B16(AH, BH, acc);   /* acc == d = hebb - p2*W */               \
    AH = *(const short8v*)(pA + (AOFF) + vA);                                 \
    AL = *(const short8v*)(pA + (AOFF) + vA + 16);                            \
    BH = *(const short8v*)(pB + (BOFF) + vB);                                 \
    SQ = *(const float4v*)(pS + (SOFF) + vS);                                 \
    const float2v d01 = __builtin_shufflevector(acc, acc, 0, 1);              \
    const float2v d23 = __builtin_shufflevector(acc, acc, 2, 3);              \
    const float2v dd2 = __builtin_elementwise_fma(d01, d01, d23 * d23);       \
    const float2v wd2 = __builtin_elementwise_fma(w01, d01, w23 * d23);       \
    const float ddt = wave_total(dd2[0] + dd2[1]);                            \
    const float wdt = wave_total(wd2[0] + wd2[1]);                            \
    const float cl = fminf(1.0f, DMAX * rsqrtf(ddt)) * SYN_LR;                \
    const float ws = fmaxf(fmaf(cl, fmaf(cl, ddt, 2.0f * wdt), wn2), 0.0f);   \
    const float wcl = fminf(1.0f, rsqrtf(ws));   /* MAX_NORM = 1 */           \
    const float ccl = wcl * cl;                                               \
    const float2v wclv = { wcl, wcl };                                        \
    const float2v cclv = { ccl, ccl };                                        \
    w01 = __builtin_elementwise_fma(d01, cclv, w01 * wclv);                   \
    w23 = __builtin_elementwise_fma(d23, cclv, w23 * wclv);                   \
    wn2 = ws * (wcl * wcl);                                                   \
  }

  for (int t = 0; t < T; t += 2) {
    STEP(Ah0, Al0, Bh0, sq0, 0, 0, 0)
    STEP(Ah1, Al1, Bh1, sq1, SA, SB, SS)
    pA += 2 * SA; pB += 2 * SB; pS += 2 * SS;
  }
#undef STEP

  out[wbase +  0] = w01[0];
  out[wbase + 16] = w01[1];
  out[wbase + 32] = w23[0];
  out[wbase + 48] = w23[1];
}

// ---------- fallback (R1-proven, no workspace needed)
__global__ __launch_bounds__(256)
void plasticity_scan_fb(const float* __restrict__ states,
                        const float* __restrict__ elig,
                        const float* __restrict__ inv,
                        const float* __restrict__ var,
                        const float* __restrict__ Win,
                        const int*   __restrict__ rows,
                        const int*   __restrict__ cols,
                        float*       __restrict__ out)
{
  __shared__ float ivs[T * B];
  __shared__ float postL[4][B * P];
  __shared__ float preL [4][B * P];

  const int tid = threadIdx.x;
  for (int k = tid; k < T * B; k += 256) ivs[k] = inv[k] * (1.0f / B);
  __syncthreads();

  const int wv   = tid >> 6;
  const int lane = tid & 63;
  const int e    = blockIdx.x * 4 + wv;
  const int irow = lane >> 2;
  const int jcol = (lane & 3) * 4;
  const int roff = rows[e] * P;
  const int coff = cols[e] * P;

  float4 w = *reinterpret_cast<const float4*>(Win + (size_t)e * 256 + lane * 4);

  const int k0 = lane, k1 = lane + 64;
  const int b0 = k0 >> 4, i0 = k0 & 15;
  const int b1 = k1 >> 4, i1 = k1 & 15;
  float* pL = postL[wv];
  float* qL = preL[wv];

  for (int t = 0; t < T; ++t) {
    const size_t base = (size_t)t * BN;
    {
      const size_t ga = base + (size_t)b0 * N + roff + i0;
      const size_t gb = base + (size_t)b1 * N + roff + i1;
      const float s0 = states[ga], v0 = var[ga];
      const float s1 = states[gb], v1 = var[gb];
      const size_t ha = base + (size_t)b0 * N + coff + i0;
      const size_t hb = base + (size_t)b1 * N + coff + i1;
      pL[k0] = v0 * (1.0f - s0 * s0);
      pL[k1] = v1 * (1.0f - s1 * s1);
      qL[k0] = elig[ha];
      qL[k1] = elig[hb];
    }
    float h0 = 0.f, h1 = 0.f, h2 = 0.f, h3 = 0.f, p2 = 0.f;
#pragma unroll
    for (int b = 0; b < B; ++b) {
      const float iv = ivs[t * B + b];
      const float pp = pL[b * 16 + irow];
      const float4 q = *reinterpret_cast<const float4*>(qL + b * 16 + jcol);
      const float pv = pp * iv;
      p2 = fmaf(pv, pp, p2);
      h0 = fmaf(pv, q.x, h0);
      h1 = fmaf(pv, q.y, h1);
      h2 = fmaf(pv, q.z, h2);
      h3 = fmaf(pv, q.w, h3);
    }
    float d0 = h0 - p2 * w.x;
    float d1 = h1 - p2 * w.y;
    float d2 = h2 - p2 * w.z;
    float d3 = h3 - p2 * w.w;
    float s = d0 * d0 + d1 * d1 + d2 * d2 + d3 * d3;
#pragma unroll
    for (int off = 32; off > 0; off >>= 1) s += __shfl_xor(s, off, 64);
    const float dn = sqrtf(s);
    const float cl = fminf(1.0f, DMAX / (dn + 1e-8f)) * SYN_LR;
    w.x = fmaf(cl, d0, w.x);
    w.y = fmaf(cl, d1, w.y);
    w.z = fmaf(cl, d2, w.z);
    w.w = fmaf(cl, d3, w.w);
    float ws = w.x * w.x + w.y * w.y + w.z * w.z + w.w * w.w;
#pragma unroll
    for (int off = 32; off > 0; off >>= 1) ws += __shfl_xor(ws, off, 64);
    const float wn = sqrtf(ws);
    const float wcl = fminf(1.0f, 1.0f / (wn + 1e-8f));
    w.x *= wcl; w.y *= wcl; w.z *= wcl; w.w *= wcl;
  }
  *reinterpret_cast<float4*>(out + (size_t)e * 256 + lane * 4) = w;
}

extern "C" void kernel_launch(void* const* d_in, const int* in_sizes, int n_in,
                              void* d_out, int out_size, void* d_ws, size_t ws_size,
                              hipStream_t stream) {
  const float* states = (const float*)d_in[0];
  const float* elig   = (const float*)d_in[1];
  // d_in[2] = act           : dead (only feeds bias, never affects W)
  const float* inv    = (const float*)d_in[3];
  const float* var    = (const float*)d_in[4];
  const float* Win    = (const float*)d_in[5];
  // d_in[6] = activity_bias : dead
  // d_in[7] = trophic_map   : dead
  const int* rows     = (const int*)d_in[8];
  const int* cols     = (const int*)d_in[9];
  // d_in[10] = active_blocks: all-ones by construction -> mask == 1.0

  float* out = (float*)d_out;

  const size_t szA  = (size_t)T * N * 32;      // 16.78 MB postT
  const size_t szB  = (size_t)T * N * 16;      //  8.39 MB preT
  const size_t szS  = (size_t)T * N * 4;       //  2.10 MB postSq
  const size_t need = szA + szB + szS + 65536; // + prefetch over-read slack
  if (ws_size >= need) {
    char* postT  = (char*)d_ws;
    char* preT   = postT + szA;
    char* postSq = preT + szB;
    prepass2<<<T * 4, 256, 0, stream>>>(states, var, elig, inv,
                                        (uint4*)postT, (uint4*)preT,
                                        (float*)postSq);
    scan_mfma<<<E / 4, 256, 0, stream>>>(postT, preT, postSq, Win,
                                         rows, cols, out);
  } else {
    plasticity_scan_fb<<<E / 4, 256, 0, stream>>>(states, elig, inv, var,
                                                  Win, rows, cols, out);
  }
}

// Round 12
// 95.360 us; speedup vs baseline: 1.1856x; 1.0178x over previous
//
#include <hip/hip_runtime.h>

// PlasticityController: T=128 sequential scan, E=4096 independent 16x16 W tiles.
// Output = W only; bias/troph updates in the reference are dead code.
//
// R12 (R11 post-mortem: cutting VALU ops didn't help -> chain-latency bound,
// not pure issue. Take the MFMA off the W-recurrence critical path):
//  - MFMA computes hebb with C=0 (independent of W) and is issued one body
//    EARLY, overlapping the previous epilogue on the VALU pipe.
//    d = pk_fma(-sq, W, hebb) afterwards (replaces the old acc-init ops).
//  - 4-deep load pipeline (slots 0..3): loads land ~3 epilogues before the
//    MFMA that consumes them -> vmcnt stalls off the chain. ~90 VGPR, still
//    4 waves/SIMD.
//  - unchanged: SGPR addressing, hi/lo bf16 split (2 MFMA), DPP reductions,
//    carried ||W||^2, rsqrt, packed fp32 epilogue.

namespace {
constexpr int T = 128, B = 8, NB = 256, P = 16;
constexpr int N = NB * P;       // 4096
constexpr int E = 4096;
constexpr int BN = B * N;       // 32768
constexpr float SYN_LR = 0.01f;
constexpr float DMAX   = 0.1f;
}

typedef __attribute__((ext_vector_type(8))) short short8v;
typedef __attribute__((ext_vector_type(4))) float float4v;
typedef __attribute__((ext_vector_type(2))) float float2v;

#if defined(__HIP_DEVICE_COMPILE__)
#define MFMA_B16(A, Bv, C) \
  __builtin_amdgcn_mfma_f32_16x16x32_bf16((A), (Bv), (C), 0, 0, 0)
#else
// host pass typechecks __global__ bodies; stub must be __device__
static __device__ inline float4v MFMA_B16(short8v, short8v, float4v C) { return C; }
#endif

__device__ __forceinline__ uint32_t bf16_rne(float x) {
  const uint32_t u = __float_as_uint(x);
  return (u + 0x7fffu + ((u >> 16) & 1u)) >> 16;
}

// ---------- DPP wave64 sum (R6-proven; wave-uniform result via readlane)
template<int CTRL>
__device__ __forceinline__ float dpp_add(float v) {
  return v + __int_as_float(__builtin_amdgcn_update_dpp(
      0, __float_as_int(v), CTRL, 0xF, 0xF, true));
}
__device__ __forceinline__ float wave_total(float v) {
  v = dpp_add<0xB1>(v);    // quad_perm [1,0,3,2]
  v = dpp_add<0x4E>(v);    // quad_perm [2,3,0,1]
  v = dpp_add<0x141>(v);   // row_half_mirror
  v = dpp_add<0x140>(v);   // row_mirror
  v = dpp_add<0x142>(v);   // row_bcast15
  v = dpp_add<0x143>(v);   // row_bcast31
  return __int_as_float(__builtin_amdgcn_readlane(__float_as_int(v), 63));
}

// ---------- prepass: packed transposed operands + postSq
// postT row (32B): 8x bf16 hi | 8x bf16 lo of 0.25*postX[b=0..7][n]
// preT  row (16B): 8x bf16 hi of preX[b=0..7][n]
// postSq[t*N+n] = sum_b postX^2 (p2 is edge-independent)
__global__ __launch_bounds__(256)
void prepass2(const float* __restrict__ states,
              const float* __restrict__ var,
              const float* __restrict__ elig,
              const float* __restrict__ inv,
              uint4* __restrict__ postT,
              uint4* __restrict__ preT,
              float* __restrict__ postSq)
{
  const int t  = blockIdx.x >> 2;
  const int n4 = ((blockIdx.x & 3) << 8) | threadIdx.x;   // 0..1023
  const int n0 = n4 * 4;
  const size_t base = (size_t)t * BN + n0;

  uint32_t ph[4][4], pl[4][4], qh[4][4];
  float sq[4] = {0.f, 0.f, 0.f, 0.f};
#pragma unroll
  for (int b = 0; b < 8; ++b) {
    const float sc = sqrtf(inv[t * B + b] * 0.125f);
    const float4 s4 = *reinterpret_cast<const float4*>(states + base + (size_t)b * N);
    const float4 v4 = *reinterpret_cast<const float4*>(var    + base + (size_t)b * N);
    const float4 e4 = *reinterpret_cast<const float4*>(elig   + base + (size_t)b * N);
    const float ss[4] = {s4.x, s4.y, s4.z, s4.w};
    const float vv[4] = {v4.x, v4.y, v4.z, v4.w};
    const float ee[4] = {e4.x, e4.y, e4.z, e4.w};
#pragma unroll
    for (int r = 0; r < 4; ++r) {
      float po = vv[r] * (1.0f - ss[r] * ss[r]) * sc;
      const float pr = ee[r] * sc;
      sq[r] = fmaf(po, po, sq[r]);     // p2 uses UNSCALED postX
      po *= 0.25f;                     // K=32 duplication counts each b 4x
      const uint32_t hp = bf16_rne(po);
      const uint32_t lp = bf16_rne(po - __uint_as_float(hp << 16));
      const uint32_t hq = bf16_rne(pr);
      if ((b & 1) == 0) {
        ph[r][b >> 1] = hp;  pl[r][b >> 1] = lp;  qh[r][b >> 1] = hq;
      } else {
        ph[r][b >> 1] |= hp << 16;  pl[r][b >> 1] |= lp << 16;
        qh[r][b >> 1] |= hq << 16;
      }
    }
  }
  const size_t row0 = (size_t)t * N + n0;
#pragma unroll
  for (int r = 0; r < 4; ++r) {
    const size_t row = row0 + r;
    postT[row * 2]     = make_uint4(ph[r][0], ph[r][1], ph[r][2], ph[r][3]);
    postT[row * 2 + 1] = make_uint4(pl[r][0], pl[r][1], pl[r][2], pl[r][3]);
    preT [row]         = make_uint4(qh[r][0], qh[r][1], qh[r][2], qh[r][3]);
  }
  *reinterpret_cast<float4*>(postSq + row0) = make_float4(sq[0], sq[1], sq[2], sq[3]);
}

// ---------- scan: MFMA decoupled from W-chain, 4-deep prefetch, zero LDS
// mfma_f32_16x16x32_bf16: A[m=l&15][k=(l>>4)*8+j], B[k][n=l&15],
// D[row=4*(l>>4)+reg][col=l&15] (layout confirmed: R9 absmax == fp32 path).
__global__ __launch_bounds__(256)
void scan_mfma(const char* __restrict__ postT,
               const char* __restrict__ preT,
               const char* __restrict__ postSq,
               const float* __restrict__ Win,
               const int* __restrict__ rows,
               const int* __restrict__ cols,
               float* __restrict__ out)
{
  const int tid  = threadIdx.x;
  const int wv   = tid >> 6;
  const int lane = tid & 63;
  const int e    = blockIdx.x * 4 + wv;
  const int g    = lane >> 4;        // 0..3
  const int c    = lane & 15;
  // wave-uniform, but divergence analysis can't see it: force SGPR
  const int roff = __builtin_amdgcn_readfirstlane(rows[e]) * P;
  const int coff = __builtin_amdgcn_readfirstlane(cols[e]) * P;

  // lane owns W[4g+r][c], r=0..3 (matches D layout)
  const size_t wbase = (size_t)e * 256 + (size_t)(4 * g) * 16 + c;
  float2v w01 = { Win[wbase +  0], Win[wbase + 16] };
  float2v w23 = { Win[wbase + 32], Win[wbase + 48] };
  const float2v t2i = __builtin_elementwise_fma(w01, w01, w23 * w23);
  float wn2 = wave_total(t2i[0] + t2i[1]);

  // uniform (SGPR) bases + constant lane offsets (VGPR)
  const char* pA = postT  + (size_t)roff * 32;
  const char* pB = preT   + (size_t)coff * 16;
  const char* pS = postSq + (size_t)roff * 4;
  const int vA = c << 5;
  const int vB = c << 4;
  const int vS = g << 4;
  constexpr int SA = N * 32, SB = N * 16, SS = N * 4;  // per-t strides

  const float4v zero4 = {0.f, 0.f, 0.f, 0.f};

  // 4-deep prefetch slots (t .. t+3)
#define LOADSLOT(i, OFF)                                           \
  short8v Ah##i = *(const short8v*)(pA + (OFF) * SA + vA);         \
  short8v Al##i = *(const short8v*)(pA + (OFF) * SA + vA + 16);    \
  short8v Bh##i = *(const short8v*)(pB + (OFF) * SB + vB);         \
  float4v sq##i = *(const float4v*)(pS + (OFF) * SS + vS);
  LOADSLOT(0, 0)
  LOADSLOT(1, 1)
  LOADSLOT(2, 2)
  LOADSLOT(3, 3)
#undef LOADSLOT
  pA += 4 * SA; pB += 4 * SB; pS += 4 * SS;

  // hebb for t=0 (C=0: independent of W)
  float4v hebbA = MFMA_B16(Ah0, Bh0, MFMA_B16(Al0, Bh0, zero4));
  float4v hebbB;

  // BODY(t): issue MFMA for t+1 (next slot), epilogue for t (cur slot),
  // reload cur slot <- t+4. Final iterations over-read <=4 strides past each
  // array; layout order postT|preT|postSq + 256KB slack keeps it in d_ws.
#define BODY(AHn, BHn, ALn, SQc, AHc, ALc, BHc, HIN, HOUT, SOFF)              \
  {                                                                           \
    HOUT = MFMA_B16(AHn, BHn, MFMA_B16(ALn, BHn, zero4));                     \
    const float2v sq01 = __builtin_shufflevector(SQc, SQc, 0, 1);             \
    const float2v sq23 = __builtin_shufflevector(SQc, SQc, 2, 3);             \
    const float2v h01  = __builtin_shufflevector(HIN, HIN, 0, 1);             \
    const float2v h23  = __builtin_shufflevector(HIN, HIN, 2, 3);             \
    const float2v d01 = __builtin_elementwise_fma(-sq01, w01, h01);           \
    const float2v d23 = __builtin_elementwise_fma(-sq23, w23, h23);           \
    AHc = *(const short8v*)(pA + (SOFF) * SA + vA);                           \
    ALc = *(const short8v*)(pA + (SOFF) * SA + vA + 16);                      \
    BHc = *(const short8v*)(pB + (SOFF) * SB + vB);                           \
    SQc = *(const float4v*)(pS + (SOFF) * SS + vS);                           \
    const float2v dd2 = __builtin_elementwise_fma(d01, d01, d23 * d23);       \
    const float2v wd2 = __builtin_elementwise_fma(w01, d01, w23 * d23);       \
    const float ddt = wave_total(dd2[0] + dd2[1]);                            \
    const float wdt = wave_total(wd2[0] + wd2[1]);                            \
    const float cl = fminf(1.0f, DMAX * rsqrtf(ddt)) * SYN_LR;                \
    const float ws = fmaxf(fmaf(cl, fmaf(cl, ddt, 2.0f * wdt), wn2), 0.0f);   \
    const float wcl = fminf(1.0f, rsqrtf(ws));   /* MAX_NORM = 1 */           \
    const float ccl = wcl * cl;                                               \
    const float2v wclv = { wcl, wcl };                                        \
    const float2v cclv = { ccl, ccl };                                        \
    w01 = __builtin_elementwise_fma(d01, cclv, w01 * wclv);                   \
    w23 = __builtin_elementwise_fma(d23, cclv, w23 * wclv);                   \
    wn2 = ws * (wcl * wcl);                                                   \
  }

  for (int t = 0; t < T; t += 4) {
    BODY(Ah1, Bh1, Al1, sq0, Ah0, Al0, Bh0, hebbA, hebbB, 0)
    BODY(Ah2, Bh2, Al2, sq1, Ah1, Al1, Bh1, hebbB, hebbA, 1)
    BODY(Ah3, Bh3, Al3, sq2, Ah2, Al2, Bh2, hebbA, hebbB, 2)
    BODY(Ah0, Bh0, Al0, sq3, Ah3, Al3, Bh3, hebbB, hebbA, 3)
    pA += 4 * SA; pB += 4 * SB; pS += 4 * SS;
  }
#undef BODY

  out[wbase +  0] = w01[0];
  out[wbase + 16] = w01[1];
  out[wbase + 32] = w23[0];
  out[wbase + 48] = w23[1];
}

// ---------- fallback (R1-proven, no workspace needed)
__global__ __launch_bounds__(256)
void plasticity_scan_fb(const float* __restrict__ states,
                        const float* __restrict__ elig,
                        const float* __restrict__ inv,
                        const float* __restrict__ var,
                        const float* __restrict__ Win,
                        const int*   __restrict__ rows,
                        const int*   __restrict__ cols,
                        float*       __restrict__ out)
{
  __shared__ float ivs[T * B];
  __shared__ float postL[4][B * P];
  __shared__ float preL [4][B * P];

  const int tid = threadIdx.x;
  for (int k = tid; k < T * B; k += 256) ivs[k] = inv[k] * (1.0f / B);
  __syncthreads();

  const int wv   = tid >> 6;
  const int lane = tid & 63;
  const int e    = blockIdx.x * 4 + wv;
  const int irow = lane >> 2;
  const int jcol = (lane & 3) * 4;
  const int roff = rows[e] * P;
  const int coff = cols[e] * P;

  float4 w = *reinterpret_cast<const float4*>(Win + (size_t)e * 256 + lane * 4);

  const int k0 = lane, k1 = lane + 64;
  const int b0 = k0 >> 4, i0 = k0 & 15;
  const int b1 = k1 >> 4, i1 = k1 & 15;
  float* pL = postL[wv];
  float* qL = preL[wv];

  for (int t = 0; t < T; ++t) {
    const size_t base = (size_t)t * BN;
    {
      const size_t ga = base + (size_t)b0 * N + roff + i0;
      const size_t gb = base + (size_t)b1 * N + roff + i1;
      const float s0 = states[ga], v0 = var[ga];
      const float s1 = states[gb], v1 = var[gb];
      const size_t ha = base + (size_t)b0 * N + coff + i0;
      const size_t hb = base + (size_t)b1 * N + coff + i1;
      pL[k0] = v0 * (1.0f - s0 * s0);
      pL[k1] = v1 * (1.0f - s1 * s1);
      qL[k0] = elig[ha];
      qL[k1] = elig[hb];
    }
    float h0 = 0.f, h1 = 0.f, h2 = 0.f, h3 = 0.f, p2 = 0.f;
#pragma unroll
    for (int b = 0; b < B; ++b) {
      const float iv = ivs[t * B + b];
      const float pp = pL[b * 16 + irow];
      const float4 q = *reinterpret_cast<const float4*>(qL + b * 16 + jcol);
      const float pv = pp * iv;
      p2 = fmaf(pv, pp, p2);
      h0 = fmaf(pv, q.x, h0);
      h1 = fmaf(pv, q.y, h1);
      h2 = fmaf(pv, q.z, h2);
      h3 = fmaf(pv, q.w, h3);
    }
    float d0 = h0 - p2 * w.x;
    float d1 = h1 - p2 * w.y;
    float d2 = h2 - p2 * w.z;
    float d3 = h3 - p2 * w.w;
    float s = d0 * d0 + d1 * d1 + d2 * d2 + d3 * d3;
#pragma unroll
    for (int off = 32; off > 0; off >>= 1) s += __shfl_xor(s, off, 64);
    const float dn = sqrtf(s);
    const float cl = fminf(1.0f, DMAX / (dn + 1e-8f)) * SYN_LR;
    w.x = fmaf(cl, d0, w.x);
    w.y = fmaf(cl, d1, w.y);
    w.z = fmaf(cl, d2, w.z);
    w.w = fmaf(cl, d3, w.w);
    float ws = w.x * w.x + w.y * w.y + w.z * w.z + w.w * w.w;
#pragma unroll
    for (int off = 32; off > 0; off >>= 1) ws += __shfl_xor(ws, off, 64);
    const float wn = sqrtf(ws);
    const float wcl = fminf(1.0f, 1.0f / (wn + 1e-8f));
    w.x *= wcl; w.y *= wcl; w.z *= wcl; w.w *= wcl;
  }
  *reinterpret_cast<float4*>(out + (size_t)e * 256 + lane * 4) = w;
}

extern "C" void kernel_launch(void* const* d_in, const int* in_sizes, int n_in,
                              void* d_out, int out_size, void* d_ws, size_t ws_size,
                              hipStream_t stream) {
  const float* states = (const float*)d_in[0];
  const float* elig   = (const float*)d_in[1];
  // d_in[2] = act           : dead (only feeds bias, never affects W)
  const float* inv    = (const float*)d_in[3];
  const float* var    = (const float*)d_in[4];
  const float* Win    = (const float*)d_in[5];
  // d_in[6] = activity_bias : dead
  // d_in[7] = trophic_map   : dead
  const int* rows     = (const int*)d_in[8];
  const int* cols     = (const int*)d_in[9];
  // d_in[10] = active_blocks: all-ones by construction -> mask == 1.0

  float* out = (float*)d_out;

  const size_t szA  = (size_t)T * N * 32;      // 16.78 MB postT
  const size_t szB  = (size_t)T * N * 16;      //  8.39 MB preT
  const size_t szS  = (size_t)T * N * 4;       //  2.10 MB postSq
  const size_t need = szA + szB + szS + 262144; // + 4-deep over-read slack
  if (ws_size >= need) {
    char* postT  = (char*)d_ws;
    char* preT   = postT + szA;
    char* postSq = preT + szB;
    prepass2<<<T * 4, 256, 0, stream>>>(states, var, elig, inv,
                                        (uint4*)postT, (uint4*)preT,
                                        (float*)postSq);
    scan_mfma<<<E / 4, 256, 0, stream>>>(postT, preT, postSq, Win,
                                         rows, cols, out);
  } else {
    plasticity_scan_fb<<<E / 4, 256, 0, stream>>>(states, elig, inv, var,
                                                  Win, rows, cols, out);
  }
}

// Round 13
// 89.474 us; speedup vs baseline: 1.2636x; 1.0658x over previous
//
#include <hip/hip_runtime.h>

// PlasticityController: T=128 sequential scan, E=4096 independent 16x16 W tiles.
// Output = W only; bias/troph updates in the reference are dead code.
//
// R13 (R12 post-mortem: measured VALUBusy implies ~140 VALU inst/wave/t vs
// ~38 written -> hidden expansion. Suspect: rsqrtf() -> OCML guarded sequence
// (10-25 inst), called 2x per t ON the critical chain):
//  - __builtin_amdgcn_rsqf: single v_rsq_f32 (~1 ulp; we already accepted
//    rsqrt accuracy in R2; threshold margin 6.4x)
//  - wn2' = fminf(ws, 1.0f): exact replacement for ws*wcl^2 (clipped -> 1.0
//    exactly, unclipped -> ws exactly); -2 inst, less approx error
//  - cl = fminf(SYN_LR, (DMAX*SYN_LR)*rsq) folds one mul; 2*wdt -> wdt+wdt
//  - unchanged: MFMA-early/C=0 decoupling, 4-deep prefetch, SGPR addressing,
//    hi/lo bf16 split, DPP reductions, packed fp32 epilogue.

namespace {
constexpr int T = 128, B = 8, NB = 256, P = 16;
constexpr int N = NB * P;       // 4096
constexpr int E = 4096;
constexpr int BN = B * N;       // 32768
constexpr float SYN_LR = 0.01f;
constexpr float DMAX   = 0.1f;
}

typedef __attribute__((ext_vector_type(8))) short short8v;
typedef __attribute__((ext_vector_type(4))) float float4v;
typedef __attribute__((ext_vector_type(2))) float float2v;

#if defined(__HIP_DEVICE_COMPILE__)
#define MFMA_B16(A, Bv, C) \
  __builtin_amdgcn_mfma_f32_16x16x32_bf16((A), (Bv), (C), 0, 0, 0)
#else
// host pass typechecks __global__ bodies; stub must be __device__
static __device__ inline float4v MFMA_B16(short8v, short8v, float4v C) { return C; }
#endif

__device__ __forceinline__ uint32_t bf16_rne(float x) {
  const uint32_t u = __float_as_uint(x);
  return (u + 0x7fffu + ((u >> 16) & 1u)) >> 16;
}

// ---------- DPP wave64 sum (R6-proven; wave-uniform result via readlane)
template<int CTRL>
__device__ __forceinline__ float dpp_add(float v) {
  return v + __int_as_float(__builtin_amdgcn_update_dpp(
      0, __float_as_int(v), CTRL, 0xF, 0xF, true));
}
__device__ __forceinline__ float wave_total(float v) {
  v = dpp_add<0xB1>(v);    // quad_perm [1,0,3,2]
  v = dpp_add<0x4E>(v);    // quad_perm [2,3,0,1]
  v = dpp_add<0x141>(v);   // row_half_mirror
  v = dpp_add<0x140>(v);   // row_mirror
  v = dpp_add<0x142>(v);   // row_bcast15
  v = dpp_add<0x143>(v);   // row_bcast31
  return __int_as_float(__builtin_amdgcn_readlane(__float_as_int(v), 63));
}

// ---------- prepass: packed transposed operands + postSq
// postT row (32B): 8x bf16 hi | 8x bf16 lo of 0.25*postX[b=0..7][n]
// preT  row (16B): 8x bf16 hi of preX[b=0..7][n]
// postSq[t*N+n] = sum_b postX^2 (p2 is edge-independent)
__global__ __launch_bounds__(256)
void prepass2(const float* __restrict__ states,
              const float* __restrict__ var,
              const float* __restrict__ elig,
              const float* __restrict__ inv,
              uint4* __restrict__ postT,
              uint4* __restrict__ preT,
              float* __restrict__ postSq)
{
  const int t  = blockIdx.x >> 2;
  const int n4 = ((blockIdx.x & 3) << 8) | threadIdx.x;   // 0..1023
  const int n0 = n4 * 4;
  const size_t base = (size_t)t * BN + n0;

  uint32_t ph[4][4], pl[4][4], qh[4][4];
  float sq[4] = {0.f, 0.f, 0.f, 0.f};
#pragma unroll
  for (int b = 0; b < 8; ++b) {
    const float sc = sqrtf(inv[t * B + b] * 0.125f);
    const float4 s4 = *reinterpret_cast<const float4*>(states + base + (size_t)b * N);
    const float4 v4 = *reinterpret_cast<const float4*>(var    + base + (size_t)b * N);
    const float4 e4 = *reinterpret_cast<const float4*>(elig   + base + (size_t)b * N);
    const float ss[4] = {s4.x, s4.y, s4.z, s4.w};
    const float vv[4] = {v4.x, v4.y, v4.z, v4.w};
    const float ee[4] = {e4.x, e4.y, e4.z, e4.w};
#pragma unroll
    for (int r = 0; r < 4; ++r) {
      float po = vv[r] * (1.0f - ss[r] * ss[r]) * sc;
      const float pr = ee[r] * sc;
      sq[r] = fmaf(po, po, sq[r]);     // p2 uses UNSCALED postX
      po *= 0.25f;                     // K=32 duplication counts each b 4x
      const uint32_t hp = bf16_rne(po);
      const uint32_t lp = bf16_rne(po - __uint_as_float(hp << 16));
      const uint32_t hq = bf16_rne(pr);
      if ((b & 1) == 0) {
        ph[r][b >> 1] = hp;  pl[r][b >> 1] = lp;  qh[r][b >> 1] = hq;
      } else {
        ph[r][b >> 1] |= hp << 16;  pl[r][b >> 1] |= lp << 16;
        qh[r][b >> 1] |= hq << 16;
      }
    }
  }
  const size_t row0 = (size_t)t * N + n0;
#pragma unroll
  for (int r = 0; r < 4; ++r) {
    const size_t row = row0 + r;
    postT[row * 2]     = make_uint4(ph[r][0], ph[r][1], ph[r][2], ph[r][3]);
    postT[row * 2 + 1] = make_uint4(pl[r][0], pl[r][1], pl[r][2], pl[r][3]);
    preT [row]         = make_uint4(qh[r][0], qh[r][1], qh[r][2], qh[r][3]);
  }
  *reinterpret_cast<float4*>(postSq + row0) = make_float4(sq[0], sq[1], sq[2], sq[3]);
}

// ---------- scan: MFMA decoupled from W-chain, 4-deep prefetch, zero LDS
// mfma_f32_16x16x32_bf16: A[m=l&15][k=(l>>4)*8+j], B[k][n=l&15],
// D[row=4*(l>>4)+reg][col=l&15] (layout confirmed: R9 absmax == fp32 path).
__global__ __launch_bounds__(256)
void scan_mfma(const char* __restrict__ postT,
               const char* __restrict__ preT,
               const char* __restrict__ postSq,
               const float* __restrict__ Win,
               const int* __restrict__ rows,
               const int* __restrict__ cols,
               float* __restrict__ out)
{
  const int tid  = threadIdx.x;
  const int wv   = tid >> 6;
  const int lane = tid & 63;
  const int e    = blockIdx.x * 4 + wv;
  const int g    = lane >> 4;        // 0..3
  const int c    = lane & 15;
  // wave-uniform, but divergence analysis can't see it: force SGPR
  const int roff = __builtin_amdgcn_readfirstlane(rows[e]) * P;
  const int coff = __builtin_amdgcn_readfirstlane(cols[e]) * P;

  // lane owns W[4g+r][c], r=0..3 (matches D layout)
  const size_t wbase = (size_t)e * 256 + (size_t)(4 * g) * 16 + c;
  float2v w01 = { Win[wbase +  0], Win[wbase + 16] };
  float2v w23 = { Win[wbase + 32], Win[wbase + 48] };
  const float2v t2i = __builtin_elementwise_fma(w01, w01, w23 * w23);
  float wn2 = wave_total(t2i[0] + t2i[1]);

  // uniform (SGPR) bases + constant lane offsets (VGPR)
  const char* pA = postT  + (size_t)roff * 32;
  const char* pB = preT   + (size_t)coff * 16;
  const char* pS = postSq + (size_t)roff * 4;
  const int vA = c << 5;
  const int vB = c << 4;
  const int vS = g << 4;
  constexpr int SA = N * 32, SB = N * 16, SS = N * 4;  // per-t strides

  const float4v zero4 = {0.f, 0.f, 0.f, 0.f};
  constexpr float DS = DMAX * SYN_LR;   // folded clip scale

  // 4-deep prefetch slots (t .. t+3)
#define LOADSLOT(i, OFF)                                           \
  short8v Ah##i = *(const short8v*)(pA + (OFF) * SA + vA);         \
  short8v Al##i = *(const short8v*)(pA + (OFF) * SA + vA + 16);    \
  short8v Bh##i = *(const short8v*)(pB + (OFF) * SB + vB);         \
  float4v sq##i = *(const float4v*)(pS + (OFF) * SS + vS);
  LOADSLOT(0, 0)
  LOADSLOT(1, 1)
  LOADSLOT(2, 2)
  LOADSLOT(3, 3)
#undef LOADSLOT
  pA += 4 * SA; pB += 4 * SB; pS += 4 * SS;

  // hebb for t=0 (C=0: independent of W)
  float4v hebbA = MFMA_B16(Ah0, Bh0, MFMA_B16(Al0, Bh0, zero4));
  float4v hebbB;

  // BODY(t): issue MFMA for t+1 (next slot), epilogue for t (cur slot),
  // reload cur slot <- t+4. Final iterations over-read <=4 strides past each
  // array; layout order postT|preT|postSq + 256KB slack keeps it in d_ws.
#define BODY(AHn, BHn, ALn, SQc, AHc, ALc, BHc, HIN, HOUT, SOFF)              \
  {                                                                           \
    HOUT = MFMA_B16(AHn, BHn, MFMA_B16(ALn, BHn, zero4));                     \
    const float2v sq01 = __builtin_shufflevector(SQc, SQc, 0, 1);             \
    const float2v sq23 = __builtin_shufflevector(SQc, SQc, 2, 3);             \
    const float2v h01  = __builtin_shufflevector(HIN, HIN, 0, 1);             \
    const float2v h23  = __builtin_shufflevector(HIN, HIN, 2, 3);             \
    const float2v d01 = __builtin_elementwise_fma(-sq01, w01, h01);           \
    const float2v d23 = __builtin_elementwise_fma(-sq23, w23, h23);           \
    AHc = *(const short8v*)(pA + (SOFF) * SA + vA);                           \
    ALc = *(const short8v*)(pA + (SOFF) * SA + vA + 16);                      \
    BHc = *(const short8v*)(pB + (SOFF) * SB + vB);                           \
    SQc = *(const float4v*)(pS + (SOFF) * SS + vS);                           \
    const float2v dd2 = __builtin_elementwise_fma(d01, d01, d23 * d23);       \
    const float2v wd2 = __builtin_elementwise_fma(w01, d01, w23 * d23);       \
    const float ddt = wave_total(dd2[0] + dd2[1]);                            \
    const float wdt = wave_total(wd2[0] + wd2[1]);                            \
    /* cl = SYN_LR*min(1, DMAX*rsq(ddt)); rsq(0)=inf -> min picks SYN_LR */   \
    const float cl = fminf(SYN_LR, DS * __builtin_amdgcn_rsqf(ddt));          \
    const float ws = fmaxf(fmaf(cl, fmaf(cl, ddt, wdt + wdt), wn2), 0.0f);    \
    const float wcl = fminf(1.0f, __builtin_amdgcn_rsqf(ws));  /* MAXN=1 */   \
    const float ccl = wcl * cl;                                               \
    const float2v wclv = { wcl, wcl };                                        \
    const float2v cclv = { ccl, ccl };                                        \
    w01 = __builtin_elementwise_fma(d01, cclv, w01 * wclv);                   \
    w23 = __builtin_elementwise_fma(d23, cclv, w23 * wclv);                   \
    /* exact: clipped -> 1, unclipped -> ws (replaces ws*wcl^2) */            \
    wn2 = fminf(ws, 1.0f);                                                    \
  }

  for (int t = 0; t < T; t += 4) {
    BODY(Ah1, Bh1, Al1, sq0, Ah0, Al0, Bh0, hebbA, hebbB, 0)
    BODY(Ah2, Bh2, Al2, sq1, Ah1, Al1, Bh1, hebbB, hebbA, 1)
    BODY(Ah3, Bh3, Al3, sq2, Ah2, Al2, Bh2, hebbA, hebbB, 2)
    BODY(Ah0, Bh0, Al0, sq3, Ah3, Al3, Bh3, hebbB, hebbA, 3)
    pA += 4 * SA; pB += 4 * SB; pS += 4 * SS;
  }
#undef BODY

  out[wbase +  0] = w01[0];
  out[wbase + 16] = w01[1];
  out[wbase + 32] = w23[0];
  out[wbase + 48] = w23[1];
}

// ---------- fallback (R1-proven, no workspace needed)
__global__ __launch_bounds__(256)
void plasticity_scan_fb(const float* __restrict__ states,
                        const float* __restrict__ elig,
                        const float* __restrict__ inv,
                        const float* __restrict__ var,
                        const float* __restrict__ Win,
                        const int*   __restrict__ rows,
                        const int*   __restrict__ cols,
                        float*       __restrict__ out)
{
  __shared__ float ivs[T * B];
  __shared__ float postL[4][B * P];
  __shared__ float preL [4][B * P];

  const int tid = threadIdx.x;
  for (int k = tid; k < T * B; k += 256) ivs[k] = inv[k] * (1.0f / B);
  __syncthreads();

  const int wv   = tid >> 6;
  const int lane = tid & 63;
  const int e    = blockIdx.x * 4 + wv;
  const int irow = lane >> 2;
  const int jcol = (lane & 3) * 4;
  const int roff = rows[e] * P;
  const int coff = cols[e] * P;

  float4 w = *reinterpret_cast<const float4*>(Win + (size_t)e * 256 + lane * 4);

  const int k0 = lane, k1 = lane + 64;
  const int b0 = k0 >> 4, i0 = k0 & 15;
  const int b1 = k1 >> 4, i1 = k1 & 15;
  float* pL = postL[wv];
  float* qL = preL[wv];

  for (int t = 0; t < T; ++t) {
    const size_t base = (size_t)t * BN;
    {
      const size_t ga = base + (size_t)b0 * N + roff + i0;
      const size_t gb = base + (size_t)b1 * N + roff + i1;
      const float s0 = states[ga], v0 = var[ga];
      const float s1 = states[gb], v1 = var[gb];
      const size_t ha = base + (size_t)b0 * N + coff + i0;
      const size_t hb = base + (size_t)b1 * N + coff + i1;
      pL[k0] = v0 * (1.0f - s0 * s0);
      pL[k1] = v1 * (1.0f - s1 * s1);
      qL[k0] = elig[ha];
      qL[k1] = elig[hb];
    }
    float h0 = 0.f, h1 = 0.f, h2 = 0.f, h3 = 0.f, p2 = 0.f;
#pragma unroll
    for (int b = 0; b < B; ++b) {
      const float iv = ivs[t * B + b];
      const float pp = pL[b * 16 + irow];
      const float4 q = *reinterpret_cast<const float4*>(qL + b * 16 + jcol);
      const float pv = pp * iv;
      p2 = fmaf(pv, pp, p2);
      h0 = fmaf(pv, q.x, h0);
      h1 = fmaf(pv, q.y, h1);
      h2 = fmaf(pv, q.z, h2);
      h3 = fmaf(pv, q.w, h3);
    }
    float d0 = h0 - p2 * w.x;
    float d1 = h1 - p2 * w.y;
    float d2 = h2 - p2 * w.z;
    float d3 = h3 - p2 * w.w;
    float s = d0 * d0 + d1 * d1 + d2 * d2 + d3 * d3;
#pragma unroll
    for (int off = 32; off > 0; off >>= 1) s += __shfl_xor(s, off, 64);
    const float dn = sqrtf(s);
    const float cl = fminf(1.0f, DMAX / (dn + 1e-8f)) * SYN_LR;
    w.x = fmaf(cl, d0, w.x);
    w.y = fmaf(cl, d1, w.y);
    w.z = fmaf(cl, d2, w.z);
    w.w = fmaf(cl, d3, w.w);
    float ws = w.x * w.x + w.y * w.y + w.z * w.z + w.w * w.w;
#pragma unroll
    for (int off = 32; off > 0; off >>= 1) ws += __shfl_xor(ws, off, 64);
    const float wn = sqrtf(ws);
    const float wcl = fminf(1.0f, 1.0f / (wn + 1e-8f));
    w.x *= wcl; w.y *= wcl; w.z *= wcl; w.w *= wcl;
  }
  *reinterpret_cast<float4*>(out + (size_t)e * 256 + lane * 4) = w;
}

extern "C" void kernel_launch(void* const* d_in, const int* in_sizes, int n_in,
                              void* d_out, int out_size, void* d_ws, size_t ws_size,
                              hipStream_t stream) {
  const float* states = (const float*)d_in[0];
  const float* elig   = (const float*)d_in[1];
  // d_in[2] = act           : dead (only feeds bias, never affects W)
  const float* inv    = (const float*)d_in[3];
  const float* var    = (const float*)d_in[4];
  const float* Win    = (const float*)d_in[5];
  // d_in[6] = activity_bias : dead
  // d_in[7] = trophic_map   : dead
  const int* rows     = (const int*)d_in[8];
  const int* cols     = (const int*)d_in[9];
  // d_in[10] = active_blocks: all-ones by construction -> mask == 1.0

  float* out = (float*)d_out;

  const size_t szA  = (size_t)T * N * 32;      // 16.78 MB postT
  const size_t szB  = (size_t)T * N * 16;      //  8.39 MB preT
  const size_t szS  = (size_t)T * N * 4;       //  2.10 MB postSq
  const size_t need = szA + szB + szS + 262144; // + 4-deep over-read slack
  if (ws_size >= need) {
    char* postT  = (char*)d_ws;
    char* preT   = postT + szA;
    char* postSq = preT + szB;
    prepass2<<<T * 4, 256, 0, stream>>>(states, var, elig, inv,
                                        (uint4*)postT, (uint4*)preT,
                                        (float*)postSq);
    scan_mfma<<<E / 4, 256, 0, stream>>>(postT, preT, postSq, Win,
                                         rows, cols, out);
  } else {
    plasticity_scan_fb<<<E / 4, 256, 0, stream>>>(states, elig, inv, var,
                                                  Win, rows, cols, out);
  }
}

// Round 14
// 76.035 us; speedup vs baseline: 1.4870x; 1.1767x over previous
//
#include <hip/hip_runtime.h>

// PlasticityController: T=128 sequential scan, E=4096 independent 16x16 W tiles.
// Output = W only; bias/troph updates in the reference are dead code.
//
// R14 (R13 post-mortem: SIMD issue port ~85% saturated -> cut instructions):
//  - joint (dd,wd) reduction via permlane32_swap: halves-swap packs dd-pairs
//    in lanes 0-31 and wd-pairs in lanes 32-63, ONE 5-level DPP butterfly
//    reduces both; readlane(31)=ddt, readlane(63)=wdt. 14 inst -> 9.
//    (reassociation only, +-ulp)
//  - hebb = Ah*Bh single MFMA (A-lo dropped too; R10 dropped B-lo).
//    Expected absmax ~2^-9 = 1.95e-3 vs threshold 6.29e-3. postT rows
//    16B hi-only: -1 load/t, FETCH -30%, prepass cheaper.
//  - unchanged: MFMA-early/C=0 decoupling, 4-deep prefetch, SGPR addressing,
//    v_rsq, exact wn2'=min(ws,1), packed fp32 epilogue.

namespace {
constexpr int T = 128, B = 8, NB = 256, P = 16;
constexpr int N = NB * P;       // 4096
constexpr int E = 4096;
constexpr int BN = B * N;       // 32768
constexpr float SYN_LR = 0.01f;
constexpr float DMAX   = 0.1f;
}

typedef __attribute__((ext_vector_type(8))) short short8v;
typedef __attribute__((ext_vector_type(4))) float float4v;
typedef __attribute__((ext_vector_type(2))) float float2v;
typedef __attribute__((ext_vector_type(2))) int   int2v;

#if defined(__HIP_DEVICE_COMPILE__)
#define MFMA_B16(A, Bv, C) \
  __builtin_amdgcn_mfma_f32_16x16x32_bf16((A), (Bv), (C), 0, 0, 0)
#define PERMSWAP(a, b) __builtin_amdgcn_permlane32_swap((a), (b), false, false)
#else
// host pass typechecks __global__ bodies; stubs must be __device__
static __device__ inline float4v MFMA_B16(short8v, short8v, float4v C) { return C; }
static __device__ inline int2v PERMSWAP(int, int) { return int2v{0, 0}; }
#endif

__device__ __forceinline__ uint32_t bf16_rne(float x) {
  const uint32_t u = __float_as_uint(x);
  return (u + 0x7fffu + ((u >> 16) & 1u)) >> 16;
}

// ---------- DPP helpers
template<int CTRL>
__device__ __forceinline__ float dpp_add(float v) {
  return v + __int_as_float(__builtin_amdgcn_update_dpp(
      0, __float_as_int(v), CTRL, 0xF, 0xF, true));
}
// full 64-lane sum, result wave-uniform (used once at init)
__device__ __forceinline__ float wave_total(float v) {
  v = dpp_add<0xB1>(v);    // quad_perm [1,0,3,2]
  v = dpp_add<0x4E>(v);    // quad_perm [2,3,0,1]
  v = dpp_add<0x141>(v);   // row_half_mirror
  v = dpp_add<0x140>(v);   // row_mirror
  v = dpp_add<0x142>(v);   // row_bcast15
  v = dpp_add<0x143>(v);   // row_bcast31
  return __int_as_float(__builtin_amdgcn_readlane(__float_as_int(v), 63));
}
// joint 64-lane sums of dd and wd in ONE butterfly:
// permlane32_swap(dd,wd): r.x = {dd.lo | wd.lo}, r.y = {dd.hi | wd.hi};
// u = r.x + r.y -> lanes 0-31: dd[l]+dd[l+32]; lanes 32-63: wd[l-32]+wd[l].
// 4-level butterfly -> 16-row sums; row_bcast15 -> row1 = ddt, row3 = wdt.
__device__ __forceinline__ void wave_total2(float dd, float wd,
                                            float& ddt, float& wdt) {
  const int2v sw = PERMSWAP(__float_as_int(dd), __float_as_int(wd));
  float u = __int_as_float(sw.x) + __int_as_float(sw.y);
  u = dpp_add<0xB1>(u);
  u = dpp_add<0x4E>(u);
  u = dpp_add<0x141>(u);
  u = dpp_add<0x140>(u);
  u = dpp_add<0x142>(u);   // row_bcast15 (rows 0,2 add 0 via bound_ctrl)
  ddt = __int_as_float(__builtin_amdgcn_readlane(__float_as_int(u), 31));
  wdt = __int_as_float(__builtin_amdgcn_readlane(__float_as_int(u), 63));
}

// ---------- prepass: packed transposed operands + postSq
// postT row (16B): 8x bf16 hi of 0.25*postX[b=0..7][n]
// preT  row (16B): 8x bf16 hi of preX[b=0..7][n]
// postSq[t*N+n] = sum_b postX^2 (p2 is edge-independent, fp32-exact)
__global__ __launch_bounds__(256)
void prepass2(const float* __restrict__ states,
              const float* __restrict__ var,
              const float* __restrict__ elig,
              const float* __restrict__ inv,
              uint4* __restrict__ postT,
              uint4* __restrict__ preT,
              float* __restrict__ postSq)
{
  const int t  = blockIdx.x >> 2;
  const int n4 = ((blockIdx.x & 3) << 8) | threadIdx.x;   // 0..1023
  const int n0 = n4 * 4;
  const size_t base = (size_t)t * BN + n0;

  uint32_t ph[4][4], qh[4][4];
  float sq[4] = {0.f, 0.f, 0.f, 0.f};
#pragma unroll
  for (int b = 0; b < 8; ++b) {
    const float sc = sqrtf(inv[t * B + b] * 0.125f);
    const float4 s4 = *reinterpret_cast<const float4*>(states + base + (size_t)b * N);
    const float4 v4 = *reinterpret_cast<const float4*>(var    + base + (size_t)b * N);
    const float4 e4 = *reinterpret_cast<const float4*>(elig   + base + (size_t)b * N);
    const float ss[4] = {s4.x, s4.y, s4.z, s4.w};
    const float vv[4] = {v4.x, v4.y, v4.z, v4.w};
    const float ee[4] = {e4.x, e4.y, e4.z, e4.w};
#pragma unroll
    for (int r = 0; r < 4; ++r) {
      float po = vv[r] * (1.0f - ss[r] * ss[r]) * sc;
      const float pr = ee[r] * sc;
      sq[r] = fmaf(po, po, sq[r]);     // p2 uses UNSCALED postX
      po *= 0.25f;                     // K=32 duplication counts each b 4x
      const uint32_t hp = bf16_rne(po);
      const uint32_t hq = bf16_rne(pr);
      if ((b & 1) == 0) {
        ph[r][b >> 1] = hp;  qh[r][b >> 1] = hq;
      } else {
        ph[r][b >> 1] |= hp << 16;  qh[r][b >> 1] |= hq << 16;
      }
    }
  }
  const size_t row0 = (size_t)t * N + n0;
#pragma unroll
  for (int r = 0; r < 4; ++r) {
    const size_t row = row0 + r;
    postT[row] = make_uint4(ph[r][0], ph[r][1], ph[r][2], ph[r][3]);
    preT [row] = make_uint4(qh[r][0], qh[r][1], qh[r][2], qh[r][3]);
  }
  *reinterpret_cast<float4*>(postSq + row0) = make_float4(sq[0], sq[1], sq[2], sq[3]);
}

// ---------- scan: 1 MFMA/t decoupled from W-chain, 4-deep prefetch, zero LDS
// mfma_f32_16x16x32_bf16: A[m=l&15][k=(l>>4)*8+j], B[k][n=l&15],
// D[row=4*(l>>4)+reg][col=l&15] (layout confirmed: R9 absmax == fp32 path).
__global__ __launch_bounds__(256)
void scan_mfma(const char* __restrict__ postT,
               const char* __restrict__ preT,
               const char* __restrict__ postSq,
               const float* __restrict__ Win,
               const int* __restrict__ rows,
               const int* __restrict__ cols,
               float* __restrict__ out)
{
  const int tid  = threadIdx.x;
  const int wv   = tid >> 6;
  const int lane = tid & 63;
  const int e    = blockIdx.x * 4 + wv;
  const int g    = lane >> 4;        // 0..3
  const int c    = lane & 15;
  // wave-uniform, but divergence analysis can't see it: force SGPR
  const int roff = __builtin_amdgcn_readfirstlane(rows[e]) * P;
  const int coff = __builtin_amdgcn_readfirstlane(cols[e]) * P;

  // lane owns W[4g+r][c], r=0..3 (matches D layout)
  const size_t wbase = (size_t)e * 256 + (size_t)(4 * g) * 16 + c;
  float2v w01 = { Win[wbase +  0], Win[wbase + 16] };
  float2v w23 = { Win[wbase + 32], Win[wbase + 48] };
  const float2v t2i = __builtin_elementwise_fma(w01, w01, w23 * w23);
  float wn2 = wave_total(t2i[0] + t2i[1]);

  // uniform (SGPR) bases + constant lane offsets (VGPR)
  const char* pA = postT  + (size_t)roff * 16;
  const char* pB = preT   + (size_t)coff * 16;
  const char* pS = postSq + (size_t)roff * 4;
  const int vA = c << 4;
  const int vB = c << 4;
  const int vS = g << 4;
  constexpr int SA = N * 16, SB = N * 16, SS = N * 4;  // per-t strides

  const float4v zero4 = {0.f, 0.f, 0.f, 0.f};
  constexpr float DS = DMAX * SYN_LR;   // folded clip scale

  // 4-deep prefetch slots (t .. t+3)
#define LOADSLOT(i, OFF)                                           \
  short8v Ah##i = *(const short8v*)(pA + (OFF) * SA + vA);         \
  short8v Bh##i = *(const short8v*)(pB + (OFF) * SB + vB);         \
  float4v sq##i = *(const float4v*)(pS + (OFF) * SS + vS);
  LOADSLOT(0, 0)
  LOADSLOT(1, 1)
  LOADSLOT(2, 2)
  LOADSLOT(3, 3)
#undef LOADSLOT
  pA += 4 * SA; pB += 4 * SB; pS += 4 * SS;

  // hebb for t=0 (C=0: independent of W)
  float4v hebbA = MFMA_B16(Ah0, Bh0, zero4);
  float4v hebbB;

  // BODY(t): issue MFMA for t+1 (next slot), epilogue for t (cur slot),
  // reload cur slot <- t+4. Final iterations over-read <=4 strides past each
  // array; layout order postT|preT|postSq + 256KB slack keeps it in d_ws.
#define BODY(AHn, BHn, SQc, AHc, BHc, HIN, HOUT, SOFF)                        \
  {                                                                           \
    HOUT = MFMA_B16(AHn, BHn, zero4);                                         \
    const float2v sq01 = __builtin_shufflevector(SQc, SQc, 0, 1);             \
    const float2v sq23 = __builtin_shufflevector(SQc, SQc, 2, 3);             \
    const float2v h01  = __builtin_shufflevector(HIN, HIN, 0, 1);             \
    const float2v h23  = __builtin_shufflevector(HIN, HIN, 2, 3);             \
    const float2v d01 = __builtin_elementwise_fma(-sq01, w01, h01);           \
    const float2v d23 = __builtin_elementwise_fma(-sq23, w23, h23);           \
    AHc = *(const short8v*)(pA + (SOFF) * SA + vA);                           \
    BHc = *(const short8v*)(pB + (SOFF) * SB + vB);                           \
    SQc = *(const float4v*)(pS + (SOFF) * SS + vS);                           \
    const float2v dd2 = __builtin_elementwise_fma(d01, d01, d23 * d23);       \
    const float2v wd2 = __builtin_elementwise_fma(w01, d01, w23 * d23);       \
    float ddt, wdt;                                                           \
    wave_total2(dd2[0] + dd2[1], wd2[0] + wd2[1], ddt, wdt);                  \
    /* cl = SYN_LR*min(1, DMAX*rsq(ddt)); rsq(0)=inf -> min picks SYN_LR */   \
    const float cl = fminf(SYN_LR, DS * __builtin_amdgcn_rsqf(ddt));          \
    const float ws = fmaxf(fmaf(cl, fmaf(cl, ddt, wdt + wdt), wn2), 0.0f);    \
    const float wcl = fminf(1.0f, __builtin_amdgcn_rsqf(ws));  /* MAXN=1 */   \
    const float ccl = wcl * cl;                                               \
    const float2v wclv = { wcl, wcl };                                        \
    const float2v cclv = { ccl, ccl };                                        \
    w01 = __builtin_elementwise_fma(d01, cclv, w01 * wclv);                   \
    w23 = __builtin_elementwise_fma(d23, cclv, w23 * wclv);                   \
    /* exact: clipped -> 1, unclipped -> ws (replaces ws*wcl^2) */            \
    wn2 = fminf(ws, 1.0f);                                                    \
  }

  for (int t = 0; t < T; t += 4) {
    BODY(Ah1, Bh1, sq0, Ah0, Bh0, hebbA, hebbB, 0)
    BODY(Ah2, Bh2, sq1, Ah1, Bh1, hebbB, hebbA, 1)
    BODY(Ah3, Bh3, sq2, Ah2, Bh2, hebbA, hebbB, 2)
    BODY(Ah0, Bh0, sq3, Ah3, Bh3, hebbB, hebbA, 3)
    pA += 4 * SA; pB += 4 * SB; pS += 4 * SS;
  }
#undef BODY

  out[wbase +  0] = w01[0];
  out[wbase + 16] = w01[1];
  out[wbase + 32] = w23[0];
  out[wbase + 48] = w23[1];
}

// ---------- fallback (R1-proven, no workspace needed)
__global__ __launch_bounds__(256)
void plasticity_scan_fb(const float* __restrict__ states,
                        const float* __restrict__ elig,
                        const float* __restrict__ inv,
                        const float* __restrict__ var,
                        const float* __restrict__ Win,
                        const int*   __restrict__ rows,
                        const int*   __restrict__ cols,
                        float*       __restrict__ out)
{
  __shared__ float ivs[T * B];
  __shared__ float postL[4][B * P];
  __shared__ float preL [4][B * P];

  const int tid = threadIdx.x;
  for (int k = tid; k < T * B; k += 256) ivs[k] = inv[k] * (1.0f / B);
  __syncthreads();

  const int wv   = tid >> 6;
  const int lane = tid & 63;
  const int e    = blockIdx.x * 4 + wv;
  const int irow = lane >> 2;
  const int jcol = (lane & 3) * 4;
  const int roff = rows[e] * P;
  const int coff = cols[e] * P;

  float4 w = *reinterpret_cast<const float4*>(Win + (size_t)e * 256 + lane * 4);

  const int k0 = lane, k1 = lane + 64;
  const int b0 = k0 >> 4, i0 = k0 & 15;
  const int b1 = k1 >> 4, i1 = k1 & 15;
  float* pL = postL[wv];
  float* qL = preL[wv];

  for (int t = 0; t < T; ++t) {
    const size_t base = (size_t)t * BN;
    {
      const size_t ga = base + (size_t)b0 * N + roff + i0;
      const size_t gb = base + (size_t)b1 * N + roff + i1;
      const float s0 = states[ga], v0 = var[ga];
      const float s1 = states[gb], v1 = var[gb];
      const size_t ha = base + (size_t)b0 * N + coff + i0;
      const size_t hb = base + (size_t)b1 * N + coff + i1;
      pL[k0] = v0 * (1.0f - s0 * s0);
      pL[k1] = v1 * (1.0f - s1 * s1);
      qL[k0] = elig[ha];
      qL[k1] = elig[hb];
    }
    float h0 = 0.f, h1 = 0.f, h2 = 0.f, h3 = 0.f, p2 = 0.f;
#pragma unroll
    for (int b = 0; b < B; ++b) {
      const float iv = ivs[t * B + b];
      const float pp = pL[b * 16 + irow];
      const float4 q = *reinterpret_cast<const float4*>(qL + b * 16 + jcol);
      const float pv = pp * iv;
      p2 = fmaf(pv, pp, p2);
      h0 = fmaf(pv, q.x, h0);
      h1 = fmaf(pv, q.y, h1);
      h2 = fmaf(pv, q.z, h2);
      h3 = fmaf(pv, q.w, h3);
    }
    float d0 = h0 - p2 * w.x;
    float d1 = h1 - p2 * w.y;
    float d2 = h2 - p2 * w.z;
    float d3 = h3 - p2 * w.w;
    float s = d0 * d0 + d1 * d1 + d2 * d2 + d3 * d3;
#pragma unroll
    for (int off = 32; off > 0; off >>= 1) s += __shfl_xor(s, off, 64);
    const float dn = sqrtf(s);
    const float cl = fminf(1.0f, DMAX / (dn + 1e-8f)) * SYN_LR;
    w.x = fmaf(cl, d0, w.x);
    w.y = fmaf(cl, d1, w.y);
    w.z = fmaf(cl, d2, w.z);
    w.w = fmaf(cl, d3, w.w);
    float ws = w.x * w.x + w.y * w.y + w.z * w.z + w.w * w.w;
#pragma unroll
    for (int off = 32; off > 0; off >>= 1) ws += __shfl_xor(ws, off, 64);
    const float wn = sqrtf(ws);
    const float wcl = fminf(1.0f, 1.0f / (wn + 1e-8f));
    w.x *= wcl; w.y *= wcl; w.z *= wcl; w.w *= wcl;
  }
  *reinterpret_cast<float4*>(out + (size_t)e * 256 + lane * 4) = w;
}

extern "C" void kernel_launch(void* const* d_in, const int* in_sizes, int n_in,
                              void* d_out, int out_size, void* d_ws, size_t ws_size,
                              hipStream_t stream) {
  const float* states = (const float*)d_in[0];
  const float* elig   = (const float*)d_in[1];
  // d_in[2] = act           : dead (only feeds bias, never affects W)
  const float* inv    = (const float*)d_in[3];
  const float* var    = (const float*)d_in[4];
  const float* Win    = (const float*)d_in[5];
  // d_in[6] = activity_bias : dead
  // d_in[7] = trophic_map   : dead
  const int* rows     = (const int*)d_in[8];
  const int* cols     = (const int*)d_in[9];
  // d_in[10] = active_blocks: all-ones by construction -> mask == 1.0

  float* out = (float*)d_out;

  const size_t szA  = (size_t)T * N * 16;      // 8.39 MB postT (hi-only)
  const size_t szB  = (size_t)T * N * 16;      // 8.39 MB preT
  const size_t szS  = (size_t)T * N * 4;       // 2.10 MB postSq
  const size_t need = szA + szB + szS + 262144; // + 4-deep over-read slack
  if (ws_size >= need) {
    char* postT  = (char*)d_ws;
    char* preT   = postT + szA;
    char* postSq = preT + szB;
    prepass2<<<T * 4, 256, 0, stream>>>(states, var, elig, inv,
                                        (uint4*)postT, (uint4*)preT,
                                        (float*)postSq);
    scan_mfma<<<E / 4, 256, 0, stream>>>(postT, preT, postSq, Win,
                                         rows, cols, out);
  } else {
    plasticity_scan_fb<<<E / 4, 256, 0, stream>>>(states, elig, inv, var,
                                                  Win, rows, cols, out);
  }
}